// Round 2
// baseline (644.798 us; speedup 1.0000x reference)
//
#include <hip/hip_runtime.h>
#include <math.h>

#define NN   65536
#define MM   512
#define CTRLD 128
#define RLEN 518
#define WLEN 1542
#define EPSF 1e-16f
#define NB   16384   // NN/4 blocks for wave-per-row kernels

__device__ __forceinline__ float softplusf_(float x){
    return x > 0.f ? x + log1pf(expf(-x)) : log1pf(expf(x));
}
__device__ __forceinline__ float sigmoidf_(float x){ return 1.f/(1.f+expf(-x)); }

__device__ __forceinline__ float blockReduce256(float v, float* red){
    int t = threadIdx.x;
    red[t] = v; __syncthreads();
    for(int s = 128; s; s >>= 1){ if(t < s) red[t] += red[t+s]; __syncthreads(); }
    float r = red[0];
    __syncthreads();
    return r;
}

__device__ __forceinline__ void waveReduce3(float& a, float& b, float& c){
    for(int o = 32; o; o >>= 1){
        a += __shfl_down(a, o);
        b += __shfl_down(b, o);
        c += __shfl_down(c, o);
    }
}
__device__ __forceinline__ void waveReduce1(float& a){
    for(int o = 32; o; o >>= 1) a += __shfl_down(a, o);
}

// ---------- init: wwn = 1/N (write wprev), wunR row0 = 1/N, pSR row0 = 1/512 ----------
__global__ void k_init(float* __restrict__ wwn, float* __restrict__ wunR0,
                       float* __restrict__ pSR0){
    int i = blockIdx.x*256 + threadIdx.x;
    wwn[i] = 1.f/NN;
    wunR0[i] = 1.f/NN;
    if(i < 512) pSR0[i] = 1.f/512.f;
}

// ---------- cont = x @ Wc.T + bc  (4x128) ----------
__global__ void k_cont(const float* __restrict__ x, const float* __restrict__ Wc,
                       const float* __restrict__ bc, float* __restrict__ cont){
    int idx = threadIdx.x;          // 512 threads
    if(idx < 4*CTRLD){
        int t = idx >> 7, c = idx & 127;
        float acc = bc[c];
        const float* xr = x + t*CTRLD;
        const float* wr = Wc + c*CTRLD;
        for(int d = 0; d < CTRLD; ++d) acc += xr[d]*wr[d];
        cont[idx] = acc;
    }
}

// ---------- ow/or for all 4 timesteps ----------
__global__ void k_owor(const float* __restrict__ cont,
                       const float* __restrict__ Ww, const float* __restrict__ bw,
                       const float* __restrict__ Wr, const float* __restrict__ br,
                       float* __restrict__ owAll, float* __restrict__ orAll){
    int idx = blockIdx.x*256 + threadIdx.x;
    if(idx < 4*WLEN){
        int t = idx / WLEN, o = idx % WLEN;
        float acc = bw[o];
        const float* cr = cont + t*CTRLD;
        const float* wr = Ww + o*CTRLD;
        for(int d = 0; d < CTRLD; ++d) acc += cr[d]*wr[d];
        owAll[idx] = acc;
    } else {
        int j = idx - 4*WLEN;
        if(j < 4*RLEN){
            int t = j / RLEN, o = j % RLEN;
            float acc = br[o];
            const float* cr = cont + t*CTRLD;
            const float* wr = Wr + o*CTRLD;
            for(int d = 0; d < CTRLD; ++d) acc += cr[d]*wr[d];
            orAll[j] = acc;
        }
    }
}

// ---------- key norms: kn[2t]=|k_w(t)|, kn[2t+1]=|k_r(t)| ----------
__global__ void k_prep(const float* __restrict__ owAll, const float* __restrict__ orAll,
                       float* __restrict__ kn){
    int t = threadIdx.x;            // 512 threads = 8 waves
    int wave = t >> 6, lane = t & 63;
    int step = wave >> 1, which = wave & 1;
    const float* base = which ? (orAll + step*RLEN) : (owAll + step*WLEN);
    float s = 0.f;
    for(int h = 0; h < 8; ++h){ float v = base[lane + h*64]; s += v*v; }
    waveReduce1(s);
    if(lane == 0) kn[wave] = sqrtf(s);
}

// ---------- step-0 write-address dot/norm on mem0 + softmax partials ----------
__global__ void k_dotn0(const float* __restrict__ mem, const float* __restrict__ ow,
                        const float* __restrict__ kn,
                        float* __restrict__ dotW, float* __restrict__ n2v,
                        float* __restrict__ pZw){
    __shared__ float kk[MM];
    __shared__ float zz[4];
    int t = threadIdx.x;
    kk[t] = ow[t]; kk[t+256] = ow[t+256];
    __syncthreads();
    int wave = t >> 6, lane = t & 63;
    int row = blockIdx.x*4 + wave;
    const float4* mrow = (const float4*)(mem + (size_t)row*MM);
    const float4* k4 = (const float4*)kk;
    float d = 0.f, n = 0.f, dummy = 0.f;
    #pragma unroll
    for(int h = 0; h < 2; ++h){
        int c = lane + h*64;
        float4 v = mrow[c];
        float4 kv = k4[c];
        d += v.x*kv.x + v.y*kv.y + v.z*kv.z + v.w*kv.w;
        n += v.x*v.x + v.y*v.y + v.z*v.z + v.w*v.w;
    }
    waveReduce3(d, n, dummy);
    if(lane == 0){
        dotW[row] = d; n2v[row] = n;
        float beta = softplusf_(ow[MM]);
        zz[wave] = expf(beta*d/(sqrtf(n)*kn[0] + EPSF));
    }
    __syncthreads();
    if(t == 0) pZw[blockIdx.x] = zz[0]+zz[1]+zz[2]+zz[3];
}

// ---------- write-address weights: wunW + pSW[256] ----------
__global__ void k_w(const float* __restrict__ ov, const float* __restrict__ dot,
                    const float* __restrict__ n2v, const float* __restrict__ pZ,
                    const float* __restrict__ wprev, const float* __restrict__ kn,
                    int knidx, float* __restrict__ wun, float* __restrict__ pS){
    __shared__ float red[256];
    int t = threadIdx.x;
    float z = 0.f;
    for(int j = t; j < NB; j += 256) z += pZ[j];
    float Z = blockReduce256(z, red);
    float beta  = softplusf_(ov[MM]);
    float g     = sigmoidf_(ov[MM+1]);
    float s0 = ov[MM+2], s1 = ov[MM+3], s2 = ov[MM+4];
    float sm = fmaxf(s0, fmaxf(s1, s2));
    float e0 = expf(s0-sm), e1 = expf(s1-sm), e2 = expf(s2-sm);
    float es = e0+e1+e2;
    s0 = e0/es; s1 = e1/es; s2 = e2/es;
    float gamma = 1.f + softplusf_(ov[MM+5]);
    float knv = kn[knidx];
    float invZ = 1.f/Z;
    int i  = blockIdx.x*256 + t;
    int im = (i-1) & (NN-1), ip = (i+1) & (NN-1);
    auto wgf = [&](int j)->float{
        float a = beta*dot[j]/(sqrtf(n2v[j])*knv + EPSF);
        return g*expf(a)*invZ + (1.f-g)*wprev[j];
    };
    float wsv = s0*wgf(im) + s1*wgf(i) + s2*wgf(ip);
    float wu = powf(wsv, gamma);
    wun[i] = wu;
    float S = blockReduce256(wu, red);
    if(t == 0) pS[blockIdx.x] = S;
}

// ---------- fused: memory update + read dot + NEXT write dot + exp partials ----------
// grid NB, block 256 (wave per row)
__global__ void k_upd(const float* msrc, float* mdst,
                      const float* __restrict__ ow, const float* __restrict__ orr,
                      const float* __restrict__ owN,
                      const float* __restrict__ wunW, const float* __restrict__ pSW,
                      const float* __restrict__ kn, int knRidx, int knWNidx,
                      float* __restrict__ wwn,
                      float* __restrict__ dotR, float* __restrict__ dotW,
                      float* __restrict__ n2v,
                      float* __restrict__ pZr, float* __restrict__ pZw){
    __shared__ float red[256];
    __shared__ float kk[MM], knx[MM], ee[MM], aa[MM];
    __shared__ float zr[4], zw[4];
    int t = threadIdx.x;
    float S = blockReduce256(pSW[t], red);
    float invS = 1.f/(S + EPSF);
    kk[t]  = orr[t];       kk[t+256]  = orr[t+256];
    knx[t] = owN[t];       knx[t+256] = owN[t+256];
    ee[t]  = sigmoidf_(ow[MM+6+t]);   ee[t+256] = sigmoidf_(ow[MM+6+256+t]);
    aa[t]  = ow[2*MM+6+t]; aa[t+256]  = ow[2*MM+6+256+t];
    __syncthreads();
    int wave = t >> 6, lane = t & 63;
    int row = blockIdx.x*4 + wave;
    float w = wunW[row]*invS;
    if(lane == 0) wwn[row] = w;
    const float4* src = (const float4*)(msrc + (size_t)row*MM);
    float4* dst = (float4*)(mdst + (size_t)row*MM);
    const float4* k4 = (const float4*)kk;
    const float4* n4 = (const float4*)knx;
    const float4* e4 = (const float4*)ee;
    const float4* a4 = (const float4*)aa;
    float d = 0.f, dn = 0.f, n = 0.f;
    #pragma unroll
    for(int h = 0; h < 2; ++h){
        int c = lane + h*64;
        float4 v = src[c];
        float4 ev = e4[c], av = a4[c], kv = k4[c], nv = n4[c];
        v.x = v.x*(1.f - w*ev.x) + w*av.x;
        v.y = v.y*(1.f - w*ev.y) + w*av.y;
        v.z = v.z*(1.f - w*ev.z) + w*av.z;
        v.w = v.w*(1.f - w*ev.w) + w*av.w;
        dst[c] = v;
        d  += v.x*kv.x + v.y*kv.y + v.z*kv.z + v.w*kv.w;
        dn += v.x*nv.x + v.y*nv.y + v.z*nv.z + v.w*nv.w;
        n  += v.x*v.x + v.y*v.y + v.z*v.z + v.w*v.w;
    }
    waveReduce3(d, dn, n);
    if(lane == 0){
        dotR[row] = d; dotW[row] = dn; n2v[row] = n;
        float sn = sqrtf(n);
        float betaR = softplusf_(orr[MM]);
        float betaW = softplusf_(owN[MM]);
        zr[wave] = expf(betaR*d /(sn*kn[knRidx]  + EPSF));
        zw[wave] = expf(betaW*dn/(sn*kn[knWNidx] + EPSF));
    }
    __syncthreads();
    if(t == 0){
        pZr[blockIdx.x] = zr[0]+zr[1]+zr[2]+zr[3];
        pZw[blockIdx.x] = zw[0]+zw[1]+zw[2]+zw[3];
    }
}

// ---------- fused read weights + r partials ----------
// grid 512, block 256; block owns 128 rows
__global__ void k_wr(const float* __restrict__ mem, const float* __restrict__ orr,
                     const float* __restrict__ dotR, const float* __restrict__ n2v,
                     const float* __restrict__ pZr,
                     const float* __restrict__ wunRp, const float* __restrict__ pSRp,
                     const float* __restrict__ kn, int knidx,
                     float* __restrict__ wunRn, float* __restrict__ pSRn,
                     float* __restrict__ rp){
    __shared__ float red[256];
    __shared__ float wsh[128];
    int t = threadIdx.x;
    float z = 0.f;
    for(int j = t; j < NB; j += 256) z += pZr[j];
    float Z = blockReduce256(z, red);
    float Sp = blockReduce256(pSRp[t] + pSRp[t+256], red);
    float invSp = 1.f/(Sp + EPSF);
    float beta  = softplusf_(orr[MM]);
    float g     = sigmoidf_(orr[MM+1]);
    float s0 = orr[MM+2], s1 = orr[MM+3], s2 = orr[MM+4];
    float sm = fmaxf(s0, fmaxf(s1, s2));
    float e0 = expf(s0-sm), e1 = expf(s1-sm), e2 = expf(s2-sm);
    float es = e0+e1+e2;
    s0 = e0/es; s1 = e1/es; s2 = e2/es;
    float gamma = 1.f + softplusf_(orr[MM+5]);
    float knv = kn[knidx];
    float invZ = 1.f/Z;
    int r0 = blockIdx.x*128;
    float wu = 0.f;
    if(t < 128){
        int i  = r0 + t;
        int im = (i-1) & (NN-1), ip = (i+1) & (NN-1);
        auto wgf = [&](int j)->float{
            float a = beta*dotR[j]/(sqrtf(n2v[j])*knv + EPSF);
            return g*expf(a)*invZ + (1.f-g)*wunRp[j]*invSp;
        };
        float wsv = s0*wgf(im) + s1*wgf(i) + s2*wgf(ip);
        wu = powf(wsv, gamma);
        wunRn[i] = wu;
        wsh[t] = wu;
    }
    float S = blockReduce256(t < 128 ? wu : 0.f, red);
    if(t == 0) pSRn[blockIdx.x] = S;
    __syncthreads();
    // phase B: rp[block][:] = sum_{r} wu[r] * mem[r0+r][:]
    const float2* m2 = (const float2*)mem;
    float ax = 0.f, ay = 0.f;
    for(int r = 0; r < 128; ++r){
        float w = wsh[r];
        float2 v = m2[(size_t)(r0 + r)*256 + t];
        ax += w*v.x; ay += w*v.y;
    }
    float2 o; o.x = ax; o.y = ay;
    ((float2*)rp)[blockIdx.x*256 + t] = o;
}

// ---------- reduce r partials (×512 blocks) + normalize ----------
__global__ void k_rsum(const float* __restrict__ rp, const float* __restrict__ pSRn,
                       float* __restrict__ rvec){
    __shared__ float red[256];
    int col = blockIdx.x, t = threadIdx.x;
    float S = blockReduce256(pSRn[t] + pSRn[t+256], red);
    float invS = 1.f/(S + EPSF);
    float s = rp[(size_t)t*512 + col] + rp[(size_t)(t+256)*512 + col];
    float r = blockReduce256(s, red);
    if(t == 0) rvec[col] = r*invS;
}

// ---------- final MLP ----------
__global__ void k_final(const float* __restrict__ cont, const float* __restrict__ rvec,
                        const float* __restrict__ W1, const float* __restrict__ b1,
                        const float* __restrict__ W2, const float* __restrict__ b2,
                        float* __restrict__ out, int step){
    __shared__ float conc[640];
    __shared__ float h[200];
    int t = threadIdx.x;
    for(int q = t; q < 640; q += 256)
        conc[q] = (q < 128) ? cont[step*128 + q] : rvec[q - 128];
    __syncthreads();
    if(t < 200){
        float acc = b1[t];
        const float* wr = W1 + t*640;
        for(int q = 0; q < 640; ++q) acc += wr[q]*conc[q];
        h[t] = fmaxf(acc, 0.f);
    }
    __syncthreads();
    if(t < 10){
        float acc = b2[t];
        const float* wr = W2 + t*200;
        for(int p = 0; p < 200; ++p) acc += wr[p]*h[p];
        out[step*10 + t] = acc;
    }
}

extern "C" void kernel_launch(void* const* d_in, const int* in_sizes, int n_in,
                              void* d_out, int out_size, void* d_ws, size_t ws_size,
                              hipStream_t stream) {
    const float* x    = (const float*)d_in[0];
    const float* mem0 = (const float*)d_in[1];
    const float* Wc   = (const float*)d_in[2];
    const float* bc   = (const float*)d_in[3];
    const float* Wr   = (const float*)d_in[4];
    const float* br   = (const float*)d_in[5];
    const float* Ww   = (const float*)d_in[6];
    const float* bw   = (const float*)d_in[7];
    const float* W1   = (const float*)d_in[8];
    const float* b1   = (const float*)d_in[9];
    const float* W2   = (const float*)d_in[10];
    const float* b2   = (const float*)d_in[11];
    float* out = (float*)d_out;

    float* ws = (float*)d_ws;
    size_t off = 0;
    float* memw  = ws + off; off += (size_t)NN*MM;   // 128 MiB
    float* dotR  = ws + off; off += NN;
    float* dotW  = ws + off; off += NN;
    float* n2v   = ws + off; off += NN;
    float* wunW  = ws + off; off += NN;
    float* wwn   = ws + off; off += NN;
    float* wunR  = ws + off; off += 2*(size_t)NN;    // double buffer
    float* pZr   = ws + off; off += NB;
    float* pZw   = ws + off; off += NB;
    float* pSW   = ws + off; off += 256;
    float* pSR   = ws + off; off += 5*512;           // row per step (+init row 0)
    float* cont  = ws + off; off += 4*CTRLD;
    float* owAll = ws + off; off += 4*WLEN;
    float* orAll = ws + off; off += 4*RLEN;
    float* kn    = ws + off; off += 8;
    float* rp    = ws + off; off += (size_t)512*512;
    float* rvec  = ws + off; off += 512;

    k_init<<<256, 256, 0, stream>>>(wwn, wunR, pSR);
    k_cont<<<1, 512, 0, stream>>>(x, Wc, bc, cont);
    k_owor<<<33, 256, 0, stream>>>(cont, Ww, bw, Wr, br, owAll, orAll);
    k_prep<<<1, 512, 0, stream>>>(owAll, orAll, kn);
    k_dotn0<<<NB, 256, 0, stream>>>(mem0, owAll, kn, dotW, n2v, pZw);

    for(int t = 0; t < 4; ++t){
        const float* ow  = owAll + t*WLEN;
        const float* orr = orAll + t*RLEN;
        int tn = (t+1 < 4) ? t+1 : 3;
        const float* owN = owAll + tn*WLEN;
        const float* msrc = (t == 0) ? mem0 : memw;

        k_w<<<256, 256, 0, stream>>>(ow, dotW, n2v, pZw, wwn, kn, 2*t, wunW, pSW);
        k_upd<<<NB, 256, 0, stream>>>(msrc, memw, ow, orr, owN, wunW, pSW,
                                      kn, 2*t+1, 2*tn, wwn, dotR, dotW, n2v, pZr, pZw);
        k_wr<<<512, 256, 0, stream>>>(memw, orr, dotR, n2v, pZr,
                                      wunR + (size_t)(t&1)*NN, pSR + t*512,
                                      kn, 2*t+1,
                                      wunR + (size_t)((t+1)&1)*NN, pSR + (t+1)*512, rp);
        k_rsum<<<512, 256, 0, stream>>>(rp, pSR + (t+1)*512, rvec);
        k_final<<<1, 256, 0, stream>>>(cont, rvec, W1, b1, W2, b2, out, t);
    }
    (void)in_sizes; (void)n_in; (void)out_size; (void)ws_size;
}

// Round 3
// 472.879 us; speedup vs baseline: 1.3636x; 1.3636x over previous
//
#include <hip/hip_runtime.h>
#include <math.h>

#define NN   65536
#define MM   512
#define CTRLD 128
#define RLEN 518
#define WLEN 1542
#define EPSF 1e-16f
#define UB   2048   // blocks for big row kernels
#define RPB  32     // rows per block
#define RPW  8      // rows per wave

__device__ __forceinline__ float softplusf_(float x){
    return x > 0.f ? x + log1pf(expf(-x)) : log1pf(expf(x));
}
__device__ __forceinline__ float sigmoidf_(float x){ return 1.f/(1.f+expf(-x)); }

__device__ __forceinline__ float blockReduce256(float v, float* red){
    int t = threadIdx.x;
    red[t] = v; __syncthreads();
    for(int s = 128; s; s >>= 1){ if(t < s) red[t] += red[t+s]; __syncthreads(); }
    float r = red[0]; __syncthreads();
    return r;
}
__device__ __forceinline__ void waveReduce3(float& a, float& b, float& c){
    for(int o = 32; o; o >>= 1){
        a += __shfl_down(a,o); b += __shfl_down(b,o); c += __shfl_down(c,o);
    }
}
__device__ __forceinline__ void waveReduce2(float& a, float& b){
    for(int o = 32; o; o >>= 1){ a += __shfl_down(a,o); b += __shfl_down(b,o); }
}
__device__ __forceinline__ void waveReduce1(float& a){
    for(int o = 32; o; o >>= 1) a += __shfl_down(a,o);
}

// ---------- init ----------
__global__ void k_init(float* __restrict__ wwn, float* __restrict__ wunR0,
                       float* __restrict__ pSR0){
    int i = blockIdx.x*256 + threadIdx.x;
    wwn[i]   = 1.f/NN;
    wunR0[i] = 1.f/NN;
    if(i < 256) pSR0[i] = 1.f/256.f;
}

// ---------- cont = x @ Wc.T + bc ----------
__global__ void k_cont(const float* __restrict__ x, const float* __restrict__ Wc,
                       const float* __restrict__ bc, float* __restrict__ cont){
    int idx = threadIdx.x;          // 512 threads
    if(idx < 4*CTRLD){
        int t = idx >> 7, c = idx & 127;
        float acc = bc[c];
        const float* xr = x + t*CTRLD;
        const float* wr = Wc + c*CTRLD;
        for(int d = 0; d < CTRLD; ++d) acc += xr[d]*wr[d];
        cont[idx] = acc;
    }
}

// ---------- controller outputs, split + aligned + pre-sigmoided e ----------
__global__ void k_owor(const float* __restrict__ cont,
                       const float* __restrict__ Ww, const float* __restrict__ bw,
                       const float* __restrict__ Wr, const float* __restrict__ br,
                       float* __restrict__ kW, float* __restrict__ sW,
                       float* __restrict__ eW, float* __restrict__ aW,
                       float* __restrict__ kR, float* __restrict__ sR){
    int idx = blockIdx.x*256 + threadIdx.x;
    if(idx < 4*WLEN){
        int t = idx / WLEN, o = idx % WLEN;
        float acc = bw[o];
        const float* cr = cont + t*CTRLD;
        const float* wr = Ww + o*CTRLD;
        for(int d = 0; d < CTRLD; ++d) acc += cr[d]*wr[d];
        if(o < 512)       kW[t*512 + o] = acc;
        else if(o < 518)  sW[t*8 + (o-512)] = acc;
        else if(o < 1030) eW[t*512 + (o-518)] = sigmoidf_(acc);
        else              aW[t*512 + (o-1030)] = acc;
    } else {
        int j = idx - 4*WLEN;
        if(j < 4*RLEN){
            int t = j / RLEN, o = j % RLEN;
            float acc = br[o];
            const float* cr = cont + t*CTRLD;
            const float* wr = Wr + o*CTRLD;
            for(int d = 0; d < CTRLD; ++d) acc += cr[d]*wr[d];
            if(o < 512) kR[t*512 + o] = acc;
            else        sR[t*8 + (o-512)] = acc;
        }
    }
}

// ---------- key norms: kn[2t]=|kW(t)|, kn[2t+1]=|kR(t)| ----------
__global__ void k_prep(const float* __restrict__ kW, const float* __restrict__ kR,
                       float* __restrict__ kn){
    int t = threadIdx.x;            // 512 threads = 8 waves
    int wave = t >> 6, lane = t & 63;
    int step = wave >> 1, which = wave & 1;
    const float* base = which ? (kR + step*512) : (kW + step*512);
    float s = 0.f;
    for(int h = 0; h < 8; ++h){ float v = base[lane + h*64]; s += v*v; }
    waveReduce1(s);
    if(lane == 0) kn[wave] = sqrtf(s);
}

// ---------- step-0 write-address dot/norm on mem0 ----------
__global__ void k_dotn0(const float* __restrict__ mem, const float* __restrict__ kW0,
                        const float* __restrict__ sW0, const float* __restrict__ kn,
                        float* __restrict__ dotW, float* __restrict__ n2v,
                        float* __restrict__ pZw){
    __shared__ float zsh[4];
    int t = threadIdx.x, wave = t >> 6, lane = t & 63;
    int c0 = lane, c1 = lane + 64;
    const float4* k4 = (const float4*)kW0;
    float4 ka = k4[c0], kb = k4[c1];
    float beta = softplusf_(sW0[0]);
    float knw = kn[0];
    float zacc = 0.f;
    int row0 = blockIdx.x*RPB + wave*RPW;
    const float4* src = (const float4*)mem;
    for(int r = 0; r < RPW; ++r){
        int row = row0 + r;
        size_t base = (size_t)row*128;
        float4 v0 = src[base + c0], v1 = src[base + c1];
        float d = v0.x*ka.x+v0.y*ka.y+v0.z*ka.z+v0.w*ka.w
                + v1.x*kb.x+v1.y*kb.y+v1.z*kb.z+v1.w*kb.w;
        float n = v0.x*v0.x+v0.y*v0.y+v0.z*v0.z+v0.w*v0.w
                + v1.x*v1.x+v1.y*v1.y+v1.z*v1.z+v1.w*v1.w;
        waveReduce2(d, n);
        if(lane == 0){
            dotW[row] = d; n2v[row] = n;
            zacc += expf(beta*d/(sqrtf(n)*knw + EPSF));
        }
    }
    if(lane == 0) zsh[wave] = zacc;
    __syncthreads();
    if(t == 0) pZw[blockIdx.x] = zsh[0]+zsh[1]+zsh[2]+zsh[3];
}

// ---------- address weights (generic: write or read head) ----------
// wprev_raw with scale invSp (pass pSp=null,256-part for read; for write wprev normalized, pSp=null)
__global__ void k_w(const float* __restrict__ sV, const float* __restrict__ dot,
                    const float* __restrict__ n2v, const float* __restrict__ pZ,
                    const float* __restrict__ wprev, const float* __restrict__ pSp,
                    const float* __restrict__ kn, int knidx,
                    float* __restrict__ wun, float* __restrict__ pS){
    __shared__ float red[256];
    int t = threadIdx.x;
    float z = 0.f;
    for(int j = t; j < UB; j += 256) z += pZ[j];
    float Z = blockReduce256(z, red);
    float invSp = 1.f;
    if(pSp){
        float Sp = blockReduce256(pSp[t], red);
        invSp = 1.f/(Sp + EPSF);
    }
    float beta  = softplusf_(sV[0]);
    float g     = sigmoidf_(sV[1]);
    float s0 = sV[2], s1 = sV[3], s2 = sV[4];
    float sm = fmaxf(s0, fmaxf(s1, s2));
    float e0 = expf(s0-sm), e1 = expf(s1-sm), e2 = expf(s2-sm);
    float es = e0+e1+e2;
    s0 = e0/es; s1 = e1/es; s2 = e2/es;
    float gamma = 1.f + softplusf_(sV[5]);
    float knv = kn[knidx];
    float invZ = 1.f/Z;
    int i  = blockIdx.x*256 + t;
    int im = (i-1) & (NN-1), ip = (i+1) & (NN-1);
    auto wgf = [&](int j)->float{
        float a = beta*dot[j]/(sqrtf(n2v[j])*knv + EPSF);
        return g*expf(a)*invZ + (1.f-g)*wprev[j]*invSp;
    };
    float wsv = s0*wgf(im) + s1*wgf(i) + s2*wgf(ip);
    float wu = powf(wsv, gamma);
    wun[i] = wu;
    float S = blockReduce256(wu, red);
    if(t == 0) pS[blockIdx.x] = S;
}

// ---------- fused: r(t-1) partials + memory update + read dot + next write dot ----------
__global__ void k_upd(const float* msrc, float* mdst,
                      const float* __restrict__ kRrow, const float* __restrict__ sRrow,
                      const float* __restrict__ kWNrow, const float* __restrict__ sWNrow,
                      const float* __restrict__ eRow, const float* __restrict__ aRow,
                      const float* __restrict__ wunW, const float* __restrict__ pSW,
                      const float* __restrict__ wunRp,
                      const float* __restrict__ kn, int knRidx, int knWidx,
                      float* __restrict__ wwn,
                      float* __restrict__ dotR, float* __restrict__ dotW,
                      float* __restrict__ n2v,
                      float* __restrict__ pZr, float* __restrict__ pZw,
                      float* __restrict__ rp, int do_rp){
    __shared__ float red[256];
    __shared__ float rps[4][512];
    __shared__ float zsh[4][2];
    int t = threadIdx.x;
    float S = blockReduce256(pSW[t], red);
    float invS = 1.f/(S + EPSF);
    int wave = t >> 6, lane = t & 63;
    int c0 = lane, c1 = lane + 64;
    const float4* kr4 = (const float4*)kRrow;
    const float4* kw4 = (const float4*)kWNrow;
    const float4* e4  = (const float4*)eRow;
    const float4* a4  = (const float4*)aRow;
    float4 kra = kr4[c0], krb = kr4[c1];
    float4 kwa = kw4[c0], kwb = kw4[c1];
    float4 ea  = e4[c0],  eb  = e4[c1];
    float4 av  = a4[c0],  bv  = a4[c1];
    float betaR = softplusf_(sRrow[0]);
    float betaW = softplusf_(sWNrow[0]);
    float knR = kn[knRidx], knW = kn[knWidx];
    float4 rpA = {0,0,0,0}, rpB = {0,0,0,0};
    float zr_acc = 0.f, zw_acc = 0.f;
    int row0 = blockIdx.x*RPB + wave*RPW;
    const float4* src = (const float4*)msrc;
    float4* dst = (float4*)mdst;
    for(int r = 0; r < RPW; ++r){
        int row = row0 + r;
        size_t base = (size_t)row*128;
        float4 v0 = src[base + c0], v1 = src[base + c1];
        if(do_rp){
            float wr = wunRp[row];
            rpA.x += wr*v0.x; rpA.y += wr*v0.y; rpA.z += wr*v0.z; rpA.w += wr*v0.w;
            rpB.x += wr*v1.x; rpB.y += wr*v1.y; rpB.z += wr*v1.z; rpB.w += wr*v1.w;
        }
        float w = wunW[row]*invS;
        if(lane == 0) wwn[row] = w;
        v0.x = v0.x*(1.f - w*ea.x) + w*av.x;
        v0.y = v0.y*(1.f - w*ea.y) + w*av.y;
        v0.z = v0.z*(1.f - w*ea.z) + w*av.z;
        v0.w = v0.w*(1.f - w*ea.w) + w*av.w;
        v1.x = v1.x*(1.f - w*eb.x) + w*bv.x;
        v1.y = v1.y*(1.f - w*eb.y) + w*bv.y;
        v1.z = v1.z*(1.f - w*eb.z) + w*bv.z;
        v1.w = v1.w*(1.f - w*eb.w) + w*bv.w;
        dst[base + c0] = v0; dst[base + c1] = v1;
        float d  = v0.x*kra.x+v0.y*kra.y+v0.z*kra.z+v0.w*kra.w
                 + v1.x*krb.x+v1.y*krb.y+v1.z*krb.z+v1.w*krb.w;
        float dn = v0.x*kwa.x+v0.y*kwa.y+v0.z*kwa.z+v0.w*kwa.w
                 + v1.x*kwb.x+v1.y*kwb.y+v1.z*kwb.z+v1.w*kwb.w;
        float n  = v0.x*v0.x+v0.y*v0.y+v0.z*v0.z+v0.w*v0.w
                 + v1.x*v1.x+v1.y*v1.y+v1.z*v1.z+v1.w*v1.w;
        waveReduce3(d, dn, n);
        if(lane == 0){
            dotR[row] = d; dotW[row] = dn; n2v[row] = n;
            float sn = sqrtf(n);
            zr_acc += expf(betaR*d /(sn*knR + EPSF));
            zw_acc += expf(betaW*dn/(sn*knW + EPSF));
        }
    }
    if(lane == 0){ zsh[wave][0] = zr_acc; zsh[wave][1] = zw_acc; }
    __syncthreads();
    if(do_rp){
        ((float4*)rps[wave])[c0] = rpA;
        ((float4*)rps[wave])[c1] = rpB;
    }
    __syncthreads();
    if(do_rp){
        rp[(size_t)blockIdx.x*512 + t]       = rps[0][t]+rps[1][t]+rps[2][t]+rps[3][t];
        rp[(size_t)blockIdx.x*512 + t + 256] = rps[0][t+256]+rps[1][t+256]+rps[2][t+256]+rps[3][t+256];
    }
    if(t == 0){
        pZr[blockIdx.x] = zsh[0][0]+zsh[1][0]+zsh[2][0]+zsh[3][0];
        pZw[blockIdx.x] = zsh[0][1]+zsh[1][1]+zsh[2][1]+zsh[3][1];
    }
}

// ---------- standalone r partials for the last step ----------
__global__ void k_rpartF(const float* __restrict__ mem, const float* __restrict__ wunR,
                         float* __restrict__ rp){
    __shared__ float rps[4][512];
    int t = threadIdx.x, wave = t >> 6, lane = t & 63;
    int c0 = lane, c1 = lane + 64;
    float4 rpA = {0,0,0,0}, rpB = {0,0,0,0};
    int row0 = blockIdx.x*RPB + wave*RPW;
    const float4* src = (const float4*)mem;
    for(int r = 0; r < RPW; ++r){
        int row = row0 + r;
        size_t base = (size_t)row*128;
        float4 v0 = src[base + c0], v1 = src[base + c1];
        float wr = wunR[row];
        rpA.x += wr*v0.x; rpA.y += wr*v0.y; rpA.z += wr*v0.z; rpA.w += wr*v0.w;
        rpB.x += wr*v1.x; rpB.y += wr*v1.y; rpB.z += wr*v1.z; rpB.w += wr*v1.w;
    }
    ((float4*)rps[wave])[c0] = rpA;
    ((float4*)rps[wave])[c1] = rpB;
    __syncthreads();
    rp[(size_t)blockIdx.x*512 + t]       = rps[0][t]+rps[1][t]+rps[2][t]+rps[3][t];
    rp[(size_t)blockIdx.x*512 + t + 256] = rps[0][t+256]+rps[1][t+256]+rps[2][t+256]+rps[3][t+256];
}

// ---------- rp[2048][512] -> p2[64][512] ----------
__global__ void k_rsumA(const float* __restrict__ rp, float* __restrict__ p2){
    int t = threadIdx.x, b = blockIdx.x;
    float ax = 0.f, ay = 0.f;
    const float2* r2 = (const float2*)rp;
    for(int j = 0; j < 32; ++j){
        float2 v = r2[(size_t)(b*32 + j)*256 + t];
        ax += v.x; ay += v.y;
    }
    float2 o; o.x = ax; o.y = ay;
    ((float2*)p2)[b*256 + t] = o;
}

// ---------- final: reduce p2, normalize, MLP ----------
__global__ void k_final(const float* __restrict__ cont, const float* __restrict__ p2,
                        const float* __restrict__ pSRn,
                        const float* __restrict__ W1, const float* __restrict__ b1,
                        const float* __restrict__ W2, const float* __restrict__ b2,
                        float* __restrict__ out, int step){
    __shared__ float red[256];
    __shared__ float conc[640];
    __shared__ float h[200];
    int t = threadIdx.x;
    float S = blockReduce256(pSRn[t], red);
    float invS = 1.f/(S + EPSF);
    float ax = 0.f, ay = 0.f;
    const float2* q = (const float2*)p2;
    for(int j = 0; j < 64; ++j){
        float2 v = q[j*256 + t];
        ax += v.x; ay += v.y;
    }
    conc[128 + 2*t]   = ax*invS;
    conc[128 + 2*t+1] = ay*invS;
    if(t < 128) conc[t] = cont[step*128 + t];
    __syncthreads();
    if(t < 200){
        float acc = b1[t];
        const float* wr = W1 + t*640;
        for(int q2 = 0; q2 < 640; ++q2) acc += wr[q2]*conc[q2];
        h[t] = fmaxf(acc, 0.f);
    }
    __syncthreads();
    if(t < 10){
        float acc = b2[t];
        const float* wr = W2 + t*200;
        for(int p = 0; p < 200; ++p) acc += wr[p]*h[p];
        out[step*10 + t] = acc;
    }
}

extern "C" void kernel_launch(void* const* d_in, const int* in_sizes, int n_in,
                              void* d_out, int out_size, void* d_ws, size_t ws_size,
                              hipStream_t stream) {
    const float* x    = (const float*)d_in[0];
    const float* mem0 = (const float*)d_in[1];
    const float* Wc   = (const float*)d_in[2];
    const float* bc   = (const float*)d_in[3];
    const float* Wr   = (const float*)d_in[4];
    const float* br   = (const float*)d_in[5];
    const float* Ww   = (const float*)d_in[6];
    const float* bw   = (const float*)d_in[7];
    const float* W1   = (const float*)d_in[8];
    const float* b1   = (const float*)d_in[9];
    const float* W2   = (const float*)d_in[10];
    const float* b2   = (const float*)d_in[11];
    float* out = (float*)d_out;

    float* ws = (float*)d_ws;
    size_t off = 0;
    float* memw  = ws + off; off += (size_t)NN*MM;   // 128 MiB
    float* dotR  = ws + off; off += NN;
    float* dotW  = ws + off; off += NN;
    float* n2v   = ws + off; off += NN;
    float* wunW  = ws + off; off += NN;
    float* wwn   = ws + off; off += NN;
    float* wunR  = ws + off; off += 2*(size_t)NN;    // double buffer
    float* pZr   = ws + off; off += UB;
    float* pZw   = ws + off; off += UB;
    float* pSW   = ws + off; off += 256;
    float* pSR   = ws + off; off += 5*256;
    float* cont  = ws + off; off += 512;
    float* kW    = ws + off; off += 4*512;
    float* sW    = ws + off; off += 4*8;
    float* eW    = ws + off; off += 4*512;
    float* aW    = ws + off; off += 4*512;
    float* kR    = ws + off; off += 4*512;
    float* sR    = ws + off; off += 4*8;
    float* kn    = ws + off; off += 16;
    float* rp    = ws + off; off += (size_t)UB*512;  // 4 MiB
    float* p2    = ws + off; off += 64*512;

    k_init<<<256, 256, 0, stream>>>(wwn, wunR, pSR);
    k_cont<<<1, 512, 0, stream>>>(x, Wc, bc, cont);
    k_owor<<<33, 256, 0, stream>>>(cont, Ww, bw, Wr, br, kW, sW, eW, aW, kR, sR);
    k_prep<<<1, 512, 0, stream>>>(kW, kR, kn);
    k_dotn0<<<UB, 256, 0, stream>>>(mem0, kW, sW, kn, dotW, n2v, pZw);

    for(int t = 0; t < 4; ++t){
        int tn = (t+1 < 4) ? t+1 : 3;
        const float* msrc = (t == 0) ? mem0 : memw;

        // write-address weights (wprev = wwn, already normalized)
        k_w<<<256, 256, 0, stream>>>(sW + t*8, dotW, n2v, pZw, wwn, (const float*)nullptr,
                                     kn, 2*t, wunW, pSW);
        // fused r(t-1)-partials + update + read dot + next write dot
        k_upd<<<UB, 256, 0, stream>>>(msrc, memw,
                                      kR + t*512, sR + t*8, kW + tn*512, sW + tn*8,
                                      eW + t*512, aW + t*512,
                                      wunW, pSW, wunR + (size_t)(t&1)*NN,
                                      kn, 2*t+1, 2*tn,
                                      wwn, dotR, dotW, n2v, pZr, pZw, rp, t > 0);
        if(t > 0){
            k_rsumA<<<64, 256, 0, stream>>>(rp, p2);
            k_final<<<1, 256, 0, stream>>>(cont, p2, pSR + t*256, W1, b1, W2, b2, out, t-1);
        }
        // read-address weights (wprev = wunR[t&1] scaled by 1/S from pSR row t)
        k_w<<<256, 256, 0, stream>>>(sR + t*8, dotR, n2v, pZr,
                                     wunR + (size_t)(t&1)*NN, pSR + t*256,
                                     kn, 2*t+1,
                                     wunR + (size_t)((t+1)&1)*NN, pSR + (t+1)*256);
    }
    // last step's r on final memory
    k_rpartF<<<UB, 256, 0, stream>>>(memw, wunR, rp);   // (3+1)&1 == 0 buffer
    k_rsumA<<<64, 256, 0, stream>>>(rp, p2);
    k_final<<<1, 256, 0, stream>>>(cont, p2, pSR + 4*256, W1, b1, W2, b2, out, 3);

    (void)in_sizes; (void)n_in; (void)out_size; (void)ws_size;
}

// Round 5
// 422.405 us; speedup vs baseline: 1.5265x; 1.1195x over previous
//
#include <hip/hip_runtime.h>
#include <math.h>

#define NN    65536
#define CTRLD 128
#define WLEN  1542
#define RLEN  518
#define EPSF  1e-16f
#define UB    2048   // blocks for big passes
#define RPB   32     // rows per block
#define RPW   8      // rows per wave

__device__ __forceinline__ float softplusf_(float x){
    return x > 0.f ? x + log1pf(expf(-x)) : log1pf(expf(x));
}
__device__ __forceinline__ float sigmoidf_(float x){ return 1.f/(1.f+expf(-x)); }

__device__ __forceinline__ float blockReduce256(float v, float* red){
    int t = threadIdx.x;
    red[t] = v; __syncthreads();
    for(int s = 128; s; s >>= 1){ if(t < s) red[t] += red[t+s]; __syncthreads(); }
    float r = red[0]; __syncthreads();
    return r;
}
__device__ __forceinline__ void waveReduce3(float& a, float& b, float& c){
    for(int o = 32; o; o >>= 1){
        a += __shfl_down(a,o); b += __shfl_down(b,o); c += __shfl_down(c,o);
    }
}
__device__ __forceinline__ void waveReduce1(float& a){
    for(int o = 32; o; o >>= 1) a += __shfl_down(a,o);
}

// ---------- fused cont + controller outputs (split, aligned, pre-sigmoided e) ----------
__global__ void k_owor(const float* __restrict__ x, const float* __restrict__ Wc,
                       const float* __restrict__ bc,
                       const float* __restrict__ Ww, const float* __restrict__ bw,
                       const float* __restrict__ Wr, const float* __restrict__ br,
                       float* __restrict__ cont,
                       float* __restrict__ kW, float* __restrict__ sW,
                       float* __restrict__ eW, float* __restrict__ aW,
                       float* __restrict__ kR, float* __restrict__ sR){
    __shared__ float cs[512];
    int tid = threadIdx.x;
    for(int q = tid; q < 512; q += 256){
        int t = q >> 7, c = q & 127;
        float acc = bc[c];
        const float* xr = x + t*CTRLD;
        const float* wr = Wc + c*CTRLD;
        for(int d = 0; d < CTRLD; ++d) acc += xr[d]*wr[d];
        cs[q] = acc;
        if(blockIdx.x == 0) cont[q] = acc;
    }
    __syncthreads();
    int idx = blockIdx.x*256 + tid;
    if(idx < 4*WLEN){
        int t = idx / WLEN, o = idx % WLEN;
        float acc = bw[o];
        const float* cr = cs + t*CTRLD;
        const float* wr = Ww + o*CTRLD;
        for(int d = 0; d < CTRLD; ++d) acc += cr[d]*wr[d];
        if(o < 512)       kW[t*512 + o] = acc;
        else if(o < 518)  sW[t*8 + (o-512)] = acc;
        else if(o < 1030) eW[t*512 + (o-518)] = sigmoidf_(acc);
        else              aW[t*512 + (o-1030)] = acc;
    } else {
        int j = idx - 4*WLEN;
        if(j < 4*RLEN){
            int t = j / RLEN, o = j % RLEN;
            float acc = br[o];
            const float* cr = cs + t*CTRLD;
            const float* wr = Wr + o*CTRLD;
            for(int d = 0; d < CTRLD; ++d) acc += cr[d]*wr[d];
            if(o < 512) kR[t*512 + o] = acc;
            else        sR[t*8 + (o-512)] = acc;
        }
    }
}

// ---------- key norms: kn[2t]=|kW(t)|, kn[2t+1]=|kR(t)| ----------
__global__ void k_prep(const float* __restrict__ kW, const float* __restrict__ kR,
                       float* __restrict__ kn){
    int t = threadIdx.x;            // 512 threads = 8 waves
    int wave = t >> 6, lane = t & 63;
    int step = wave >> 1, which = wave & 1;
    const float* base = which ? (kR + step*512) : (kW + step*512);
    float s = 0.f;
    for(int h = 0; h < 8; ++h){ float v = base[lane + h*64]; s += v*v; }
    waveReduce1(s);
    if(lane == 0) kn[wave] = sqrtf(s);
}

// ---------- the mega pass: recompute chain + optional rp / update / dots ----------
// CH: number of chained writes applied before RP (recovers M_{CH-1})
// RP: accumulate r(CH-1) partials with RAW wunR[CH-1] (normalized later in k_final)
// UPD: apply write CH (giving M_CH)
// DOTR/DOTW: dot current memory with kRc / kWn (+ n2, exp partials)
template<int CH, bool RP, bool UPD, bool DOTR, bool DOTW>
__global__ __launch_bounds__(256) void k_mega(
    const float* __restrict__ mem0,
    const float* __restrict__ wunWall, const float* __restrict__ pSWall,
    const float* __restrict__ wunRall,
    const float* __restrict__ eW, const float* __restrict__ aW,
    const float* __restrict__ kRc, const float* __restrict__ sRc,
    const float* __restrict__ kWn, const float* __restrict__ sWn,
    const float* __restrict__ kn, int knRidx, int knWidx,
    float* __restrict__ dotRo, float* __restrict__ dotWo, float* __restrict__ n2o,
    float* __restrict__ pZr, float* __restrict__ pZw, float* __restrict__ rp)
{
    constexpr int NW = CH + (UPD ? 1 : 0);
    constexpr int NA = NW > 0 ? NW : 1;
    __shared__ float red[256];
    __shared__ float zsh[4][2];
    __shared__ float rps[4][512];
    int t = threadIdx.x;
    float wnorm[NA];
    #pragma unroll
    for(int j = 0; j < NW; ++j)
        wnorm[j] = 1.f/(blockReduce256(pSWall[j*256 + t], red) + EPSF);

    int wave = t >> 6, lane = t & 63;
    int c0 = lane, c1 = lane + 64;
    float4 ev0[NA], ev1[NA], av0[NA], av1[NA];
    #pragma unroll
    for(int j = 0; j < NW; ++j){
        ev0[j] = ((const float4*)(eW + j*512))[c0];
        ev1[j] = ((const float4*)(eW + j*512))[c1];
        av0[j] = ((const float4*)(aW + j*512))[c0];
        av1[j] = ((const float4*)(aW + j*512))[c1];
    }
    float4 kra, krb, kwa, kwb;
    float betaR = 0.f, betaW = 0.f, knRv = 1.f, knWv = 1.f;
    if constexpr(DOTR){
        kra = ((const float4*)kRc)[c0]; krb = ((const float4*)kRc)[c1];
        betaR = softplusf_(sRc[0]); knRv = kn[knRidx];
    }
    if constexpr(DOTW){
        kwa = ((const float4*)kWn)[c0]; kwb = ((const float4*)kWn)[c1];
        betaW = softplusf_(sWn[0]); knWv = kn[knWidx];
    }
    float4 rpA = {0,0,0,0}, rpB = {0,0,0,0};
    float zr = 0.f, zw = 0.f;
    int row0 = blockIdx.x*RPB + wave*RPW;
    const float4* src = (const float4*)mem0;
    for(int r = 0; r < RPW; ++r){
        int row = row0 + r;
        size_t base = (size_t)row*128;
        float4 v0 = src[base + c0], v1 = src[base + c1];
        #pragma unroll
        for(int j = 0; j < CH; ++j){
            float w = wunWall[(size_t)j*NN + row]*wnorm[j];
            v0.x = v0.x*(1.f - w*ev0[j].x) + w*av0[j].x;
            v0.y = v0.y*(1.f - w*ev0[j].y) + w*av0[j].y;
            v0.z = v0.z*(1.f - w*ev0[j].z) + w*av0[j].z;
            v0.w = v0.w*(1.f - w*ev0[j].w) + w*av0[j].w;
            v1.x = v1.x*(1.f - w*ev1[j].x) + w*av1[j].x;
            v1.y = v1.y*(1.f - w*ev1[j].y) + w*av1[j].y;
            v1.z = v1.z*(1.f - w*ev1[j].z) + w*av1[j].z;
            v1.w = v1.w*(1.f - w*ev1[j].w) + w*av1[j].w;
        }
        if constexpr(RP){
            float wr = wunRall[(size_t)(CH-1)*NN + row];   // RAW; normalized once in k_final
            rpA.x += wr*v0.x; rpA.y += wr*v0.y; rpA.z += wr*v0.z; rpA.w += wr*v0.w;
            rpB.x += wr*v1.x; rpB.y += wr*v1.y; rpB.z += wr*v1.z; rpB.w += wr*v1.w;
        }
        if constexpr(UPD){
            float w = wunWall[(size_t)CH*NN + row]*wnorm[CH];
            v0.x = v0.x*(1.f - w*ev0[CH].x) + w*av0[CH].x;
            v0.y = v0.y*(1.f - w*ev0[CH].y) + w*av0[CH].y;
            v0.z = v0.z*(1.f - w*ev0[CH].z) + w*av0[CH].z;
            v0.w = v0.w*(1.f - w*ev0[CH].w) + w*av0[CH].w;
            v1.x = v1.x*(1.f - w*ev1[CH].x) + w*av1[CH].x;
            v1.y = v1.y*(1.f - w*ev1[CH].y) + w*av1[CH].y;
            v1.z = v1.z*(1.f - w*ev1[CH].z) + w*av1[CH].z;
            v1.w = v1.w*(1.f - w*ev1[CH].w) + w*av1[CH].w;
        }
        if constexpr(DOTR || DOTW){
            float d = 0.f, dn = 0.f;
            float n = v0.x*v0.x+v0.y*v0.y+v0.z*v0.z+v0.w*v0.w
                    + v1.x*v1.x+v1.y*v1.y+v1.z*v1.z+v1.w*v1.w;
            if constexpr(DOTR)
                d = v0.x*kra.x+v0.y*kra.y+v0.z*kra.z+v0.w*kra.w
                  + v1.x*krb.x+v1.y*krb.y+v1.z*krb.z+v1.w*krb.w;
            if constexpr(DOTW)
                dn = v0.x*kwa.x+v0.y*kwa.y+v0.z*kwa.z+v0.w*kwa.w
                   + v1.x*kwb.x+v1.y*kwb.y+v1.z*kwb.z+v1.w*kwb.w;
            waveReduce3(d, dn, n);
            if(lane == 0){
                n2o[row] = n;
                float sn = sqrtf(n);
                if constexpr(DOTR){ dotRo[row] = d;  zr += expf(betaR*d /(sn*knRv + EPSF)); }
                if constexpr(DOTW){ dotWo[row] = dn; zw += expf(betaW*dn/(sn*knWv + EPSF)); }
            }
        }
    }
    if constexpr(DOTR || DOTW){
        if(lane == 0){ zsh[wave][0] = zr; zsh[wave][1] = zw; }
    }
    __syncthreads();
    if constexpr(RP){
        ((float4*)rps[wave])[c0] = rpA;
        ((float4*)rps[wave])[c1] = rpB;
        __syncthreads();
        rp[(size_t)blockIdx.x*512 + t]       = rps[0][t]+rps[1][t]+rps[2][t]+rps[3][t];
        rp[(size_t)blockIdx.x*512 + t + 256] = rps[0][t+256]+rps[1][t+256]+rps[2][t+256]+rps[3][t+256];
    }
    if(t == 0){
        if constexpr(DOTR) pZr[blockIdx.x] = zsh[0][0]+zsh[1][0]+zsh[2][0]+zsh[3][0];
        if constexpr(DOTW) pZw[blockIdx.x] = zsh[0][1]+zsh[1][1]+zsh[2][1]+zsh[3][1];
    }
}

// ---------- step-0 write-address weights (wprev = 1/N analytic) ----------
__global__ void k_w0(const float* __restrict__ sW0, const float* __restrict__ dot,
                     const float* __restrict__ n2v, const float* __restrict__ pZ,
                     const float* __restrict__ kn,
                     float* __restrict__ wun, float* __restrict__ pS){
    __shared__ float red[256];
    int t = threadIdx.x;
    float z = 0.f;
    for(int j = t; j < UB; j += 256) z += pZ[j];
    float Z = blockReduce256(z, red);
    float beta  = softplusf_(sW0[0]);
    float g     = sigmoidf_(sW0[1]);
    float s0 = sW0[2], s1 = sW0[3], s2 = sW0[4];
    float sm = fmaxf(s0, fmaxf(s1, s2));
    float e0 = expf(s0-sm), e1 = expf(s1-sm), e2 = expf(s2-sm);
    float es = e0+e1+e2;
    s0 = e0/es; s1 = e1/es; s2 = e2/es;
    float gamma = 1.f + softplusf_(sW0[5]);
    float knv = kn[0];
    float invZ = 1.f/Z;
    int i  = blockIdx.x*256 + t;
    int im = (i-1) & (NN-1), ip = (i+1) & (NN-1);
    auto wgf = [&](int j)->float{
        float a = beta*dot[j]/(sqrtf(n2v[j])*knv + EPSF);
        return g*expf(a)*invZ + (1.f-g)*(1.f/NN);
    };
    float wsv = s0*wgf(im) + s1*wgf(i) + s2*wgf(ip);
    float wu = powf(wsv, gamma);
    wun[i] = wu;
    float S = blockReduce256(wu, red);
    if(t == 0) pS[blockIdx.x] = S;
}

// ---------- per-step pair: read-head w_r(t) and (optional) write-head w_w(t+1) ----------
__global__ void k_w2(const float* __restrict__ sRt, const float* __restrict__ dotRv,
                     const float* __restrict__ n2v, const float* __restrict__ pZr,
                     const float* __restrict__ wunRprev, const float* __restrict__ pSRprev,
                     const float* __restrict__ kn, int knRidx,
                     float* __restrict__ wunRout, float* __restrict__ pSRout,
                     int doW,
                     const float* __restrict__ sWn, const float* __restrict__ dotWv,
                     const float* __restrict__ pZw,
                     const float* __restrict__ wunWprev, const float* __restrict__ pSWprev,
                     int knWidx,
                     float* __restrict__ wunWout, float* __restrict__ pSWout){
    __shared__ float red[256];
    int t = threadIdx.x;
    int i  = blockIdx.x*256 + t;
    int im = (i-1) & (NN-1), ip = (i+1) & (NN-1);
    // ---- read head ----
    {
        float z = 0.f;
        for(int j = t; j < UB; j += 256) z += pZr[j];
        float Z = blockReduce256(z, red);
        float invSp = 1.f;
        if(pSRprev) invSp = 1.f/(blockReduce256(pSRprev[t], red) + EPSF);
        float beta  = softplusf_(sRt[0]);
        float g     = sigmoidf_(sRt[1]);
        float s0 = sRt[2], s1 = sRt[3], s2 = sRt[4];
        float sm = fmaxf(s0, fmaxf(s1, s2));
        float e0 = expf(s0-sm), e1 = expf(s1-sm), e2 = expf(s2-sm);
        float es = e0+e1+e2;
        s0 = e0/es; s1 = e1/es; s2 = e2/es;
        float gamma = 1.f + softplusf_(sRt[5]);
        float knv = kn[knRidx];
        float invZ = 1.f/Z;
        auto wgf = [&](int j)->float{
            float a = beta*dotRv[j]/(sqrtf(n2v[j])*knv + EPSF);
            float pv = wunRprev ? wunRprev[j]*invSp : (1.f/NN);
            return g*expf(a)*invZ + (1.f-g)*pv;
        };
        float wsv = s0*wgf(im) + s1*wgf(i) + s2*wgf(ip);
        float wu = powf(wsv, gamma);
        wunRout[i] = wu;
        float S = blockReduce256(wu, red);
        if(t == 0) pSRout[blockIdx.x] = S;
    }
    // ---- write head (next step) ----
    if(doW){
        float z = 0.f;
        for(int j = t; j < UB; j += 256) z += pZw[j];
        float Z = blockReduce256(z, red);
        float invSp = 1.f/(blockReduce256(pSWprev[t], red) + EPSF);
        float beta  = softplusf_(sWn[0]);
        float g     = sigmoidf_(sWn[1]);
        float s0 = sWn[2], s1 = sWn[3], s2 = sWn[4];
        float sm = fmaxf(s0, fmaxf(s1, s2));
        float e0 = expf(s0-sm), e1 = expf(s1-sm), e2 = expf(s2-sm);
        float es = e0+e1+e2;
        s0 = e0/es; s1 = e1/es; s2 = e2/es;
        float gamma = 1.f + softplusf_(sWn[5]);
        float knv = kn[knWidx];
        float invZ = 1.f/Z;
        auto wgf = [&](int j)->float{
            float a = beta*dotWv[j]/(sqrtf(n2v[j])*knv + EPSF);
            return g*expf(a)*invZ + (1.f-g)*wunWprev[j]*invSp;
        };
        float wsv = s0*wgf(im) + s1*wgf(i) + s2*wgf(ip);
        float wu = powf(wsv, gamma);
        wunWout[i] = wu;
        float S = blockReduce256(wu, red);
        if(t == 0) pSWout[blockIdx.x] = S;
    }
}

// ---------- rp[2048][512] -> p2[64][512] ----------
__global__ void k_rsumA(const float* __restrict__ rp, float* __restrict__ p2){
    int t = threadIdx.x, b = blockIdx.x;
    float ax = 0.f, ay = 0.f;
    const float2* r2 = (const float2*)rp;
    for(int j = 0; j < 32; ++j){
        float2 v = r2[(size_t)(b*32 + j)*256 + t];
        ax += v.x; ay += v.y;
    }
    float2 o; o.x = ax; o.y = ay;
    ((float2*)p2)[b*256 + t] = o;
}

// ---------- final: reduce p2, normalize, MLP ----------
__global__ void k_final(const float* __restrict__ cont, const float* __restrict__ p2,
                        const float* __restrict__ pSRn,
                        const float* __restrict__ W1, const float* __restrict__ b1,
                        const float* __restrict__ W2, const float* __restrict__ b2,
                        float* __restrict__ out, int step){
    __shared__ float red[256];
    __shared__ float conc[640];
    __shared__ float h[200];
    int t = threadIdx.x;
    float S = blockReduce256(pSRn[t], red);
    float invS = 1.f/(S + EPSF);
    float ax = 0.f, ay = 0.f;
    const float2* q = (const float2*)p2;
    for(int j = 0; j < 64; ++j){
        float2 v = q[j*256 + t];
        ax += v.x; ay += v.y;
    }
    conc[128 + 2*t]   = ax*invS;
    conc[128 + 2*t+1] = ay*invS;
    if(t < 128) conc[t] = cont[step*128 + t];
    __syncthreads();
    if(t < 200){
        float acc = b1[t];
        const float* wr = W1 + t*640;
        for(int q2 = 0; q2 < 640; ++q2) acc += wr[q2]*conc[q2];
        h[t] = fmaxf(acc, 0.f);
    }
    __syncthreads();
    if(t < 10){
        float acc = b2[t];
        const float* wr = W2 + t*200;
        for(int p = 0; p < 200; ++p) acc += wr[p]*h[p];
        out[step*10 + t] = acc;
    }
}

extern "C" void kernel_launch(void* const* d_in, const int* in_sizes, int n_in,
                              void* d_out, int out_size, void* d_ws, size_t ws_size,
                              hipStream_t stream) {
    const float* x    = (const float*)d_in[0];
    const float* mem0 = (const float*)d_in[1];
    const float* Wc   = (const float*)d_in[2];
    const float* bc   = (const float*)d_in[3];
    const float* Wr   = (const float*)d_in[4];
    const float* br   = (const float*)d_in[5];
    const float* Ww   = (const float*)d_in[6];
    const float* bw   = (const float*)d_in[7];
    const float* W1   = (const float*)d_in[8];
    const float* b1   = (const float*)d_in[9];
    const float* W2   = (const float*)d_in[10];
    const float* b2   = (const float*)d_in[11];
    float* out = (float*)d_out;

    float* ws = (float*)d_ws;
    size_t off = 0;
    float* wunW = ws + off; off += 4*(size_t)NN;
    float* pSW  = ws + off; off += 4*256;
    float* wunR = ws + off; off += 4*(size_t)NN;
    float* pSR  = ws + off; off += 4*256;
    float* dotR = ws + off; off += NN;
    float* dotW = ws + off; off += NN;
    float* n2v  = ws + off; off += NN;
    float* pZr  = ws + off; off += UB;
    float* pZw  = ws + off; off += UB;
    float* cont = ws + off; off += 512;
    float* kW   = ws + off; off += 4*512;
    float* sW   = ws + off; off += 4*8;
    float* eW   = ws + off; off += 4*512;
    float* aW   = ws + off; off += 4*512;
    float* kR   = ws + off; off += 4*512;
    float* sR   = ws + off; off += 4*8;
    float* kn   = ws + off; off += 16;
    float* rp   = ws + off; off += (size_t)UB*512;
    float* p2   = ws + off; off += 64*512;

    k_owor<<<33, 256, 0, stream>>>(x, Wc, bc, Ww, bw, Wr, br,
                                   cont, kW, sW, eW, aW, kR, sR);
    k_prep<<<1, 512, 0, stream>>>(kW, kR, kn);

    // pass 1: write-0 addressing dots on mem0
    k_mega<0,false,false,false,true><<<UB, 256, 0, stream>>>(
        mem0, wunW, pSW, wunR, eW, aW,
        nullptr, nullptr, kW, sW, kn, 0, 0,
        dotR, dotW, n2v, pZr, pZw, rp);
    k_w0<<<256, 256, 0, stream>>>(sW, dotW, n2v, pZw, kn, wunW, pSW);

    // U0: apply write0, dots for read0 + write1
    k_mega<0,false,true,true,true><<<UB, 256, 0, stream>>>(
        mem0, wunW, pSW, wunR, eW, aW,
        kR, sR, kW + 512, sW + 8, kn, 1, 2,
        dotR, dotW, n2v, pZr, pZw, rp);
    k_w2<<<256, 256, 0, stream>>>(sR, dotR, n2v, pZr,
                                  nullptr, nullptr, kn, 1,
                                  wunR, pSR, 1,
                                  sW + 8, dotW, pZw, wunW, pSW, 2,
                                  wunW + NN, pSW + 256);

    // U1: recompute M_0, r(0) partials, apply write1, dots read1 + write2
    k_mega<1,true,true,true,true><<<UB, 256, 0, stream>>>(
        mem0, wunW, pSW, wunR, eW, aW,
        kR + 512, sR + 8, kW + 1024, sW + 16, kn, 3, 4,
        dotR, dotW, n2v, pZr, pZw, rp);
    k_w2<<<256, 256, 0, stream>>>(sR + 8, dotR, n2v, pZr,
                                  wunR, pSR, kn, 3,
                                  wunR + NN, pSR + 256, 1,
                                  sW + 16, dotW, pZw, wunW + NN, pSW + 256, 4,
                                  wunW + 2*(size_t)NN, pSW + 512);
    k_rsumA<<<64, 256, 0, stream>>>(rp, p2);
    k_final<<<1, 256, 0, stream>>>(cont, p2, pSR, W1, b1, W2, b2, out, 0);

    // U2
    k_mega<2,true,true,true,true><<<UB, 256, 0, stream>>>(
        mem0, wunW, pSW, wunR, eW, aW,
        kR + 1024, sR + 16, kW + 1536, sW + 24, kn, 5, 6,
        dotR, dotW, n2v, pZr, pZw, rp);
    k_w2<<<256, 256, 0, stream>>>(sR + 16, dotR, n2v, pZr,
                                  wunR + NN, pSR + 256, kn, 5,
                                  wunR + 2*(size_t)NN, pSR + 512, 1,
                                  sW + 24, dotW, pZw, wunW + 2*(size_t)NN, pSW + 512, 6,
                                  wunW + 3*(size_t)NN, pSW + 768);
    k_rsumA<<<64, 256, 0, stream>>>(rp, p2);
    k_final<<<1, 256, 0, stream>>>(cont, p2, pSR + 256, W1, b1, W2, b2, out, 1);

    // U3 (no next write head)
    k_mega<3,true,true,true,false><<<UB, 256, 0, stream>>>(
        mem0, wunW, pSW, wunR, eW, aW,
        kR + 1536, sR + 24, nullptr, nullptr, kn, 7, 0,
        dotR, dotW, n2v, pZr, pZw, rp);
    k_w2<<<256, 256, 0, stream>>>(sR + 24, dotR, n2v, pZr,
                                  wunR + 2*(size_t)NN, pSR + 512, kn, 7,
                                  wunR + 3*(size_t)NN, pSR + 768, 0,
                                  nullptr, nullptr, nullptr, nullptr, nullptr, 0,
                                  nullptr, nullptr);
    k_rsumA<<<64, 256, 0, stream>>>(rp, p2);
    k_final<<<1, 256, 0, stream>>>(cont, p2, pSR + 512, W1, b1, W2, b2, out, 2);

    // U4: final r on M_3
    k_mega<4,true,false,false,false><<<UB, 256, 0, stream>>>(
        mem0, wunW, pSW, wunR, eW, aW,
        nullptr, nullptr, nullptr, nullptr, kn, 0, 0,
        dotR, dotW, n2v, pZr, pZw, rp);
    k_rsumA<<<64, 256, 0, stream>>>(rp, p2);
    k_final<<<1, 256, 0, stream>>>(cont, p2, pSR + 768, W1, b1, W2, b2, out, 3);

    (void)in_sizes; (void)n_in; (void)out_size; (void)ws_size;
}

// Round 6
// 393.100 us; speedup vs baseline: 1.6403x; 1.0745x over previous
//
#include <hip/hip_runtime.h>
#include <hip/hip_cooperative_groups.h>
#include <math.h>

namespace cg = cooperative_groups;

#define NN    65536
#define CTRLD 128
#define WLEN  1542
#define RLEN  518
#define EPSF  1e-16f
#define GRIDB 1024
#define ROWSB 64     // rows per block
#define RPWV  16     // rows per wave

struct KP {
  const float* mem0; const float* cont;
  const float* kW; const float* sW; const float* eW; const float* aW;
  const float* kR; const float* sR; const float* kn;
  float *dotR, *dotW, *n2v;
  float *wunW, *pSW, *wunR, *pSR;
  float *pZr, *pZw;
  float *rp, *p2, *hbuf;
  const float *W1, *b1, *W2, *b2;
  float* out;
};

struct Smem { float red[256]; float big[2048]; float zsh[4][2]; };

__device__ __forceinline__ float softplusf_(float x){
    return x > 0.f ? x + log1pf(expf(-x)) : log1pf(expf(x));
}
__device__ __forceinline__ float sigmoidf_(float x){ return 1.f/(1.f+expf(-x)); }

__device__ __forceinline__ float blockReduce256(float v, float* red){
    int t = threadIdx.x;
    red[t] = v; __syncthreads();
    for(int s = 128; s; s >>= 1){ if(t < s) red[t] += red[t+s]; __syncthreads(); }
    float r = red[0]; __syncthreads();
    return r;
}
__device__ __forceinline__ void waveReduce3(float& a, float& b, float& c){
    for(int o = 32; o; o >>= 1){
        a += __shfl_down(a,o); b += __shfl_down(b,o); c += __shfl_down(c,o);
    }
}
__device__ __forceinline__ void waveReduce1(float& a){
    for(int o = 32; o; o >>= 1) a += __shfl_down(a,o);
}

// ================= sweep phase =================
// CH writes applied -> M_{CH-1}; RP: r partials with RAW wunR[rstep]; UPD: apply
// write CH; DOTR/DOTW: dots vs kRc/kWn on current memory + exp partials.
template<int CH, bool RP, bool UPD, bool DOTR, bool DOTW>
__device__ __forceinline__ void sweep_phase(const KP& p, Smem& sm, int rstep,
    const float* kRc, const float* sRc, int knRi,
    const float* kWn, const float* sWn, int knWi)
{
    constexpr int NW = CH + (UPD ? 1 : 0);
    constexpr int NA = (NW > 0) ? NW : 1;
    int t = threadIdx.x, bid = blockIdx.x;
    float wnorm[NA];
    #pragma unroll
    for(int j = 0; j < NW; ++j){
        float s = p.pSW[j*GRIDB+t] + p.pSW[j*GRIDB+t+256]
                + p.pSW[j*GRIDB+t+512] + p.pSW[j*GRIDB+t+768];
        wnorm[j] = 1.f/(blockReduce256(s, sm.red) + EPSF);
    }
    int wave = t >> 6, lane = t & 63;
    int c0 = lane, c1 = lane + 64;
    float4 ev0[NA], ev1[NA], av0[NA], av1[NA];
    #pragma unroll
    for(int j = 0; j < NW; ++j){
        ev0[j] = ((const float4*)(p.eW + j*512))[c0];
        ev1[j] = ((const float4*)(p.eW + j*512))[c1];
        av0[j] = ((const float4*)(p.aW + j*512))[c0];
        av1[j] = ((const float4*)(p.aW + j*512))[c1];
    }
    float4 kra, krb, kwa, kwb;
    float betaR = 0.f, betaW = 0.f, knRv = 1.f, knWv = 1.f;
    if constexpr(DOTR){
        kra = ((const float4*)kRc)[c0]; krb = ((const float4*)kRc)[c1];
        betaR = softplusf_(sRc[0]); knRv = p.kn[knRi];
    }
    if constexpr(DOTW){
        kwa = ((const float4*)kWn)[c0]; kwb = ((const float4*)kWn)[c1];
        betaW = softplusf_(sWn[0]); knWv = p.kn[knWi];
    }
    float4 rpA = {0,0,0,0}, rpB = {0,0,0,0};
    float zr = 0.f, zw = 0.f;
    int row0 = bid*ROWSB + wave*RPWV;
    const float4* src = (const float4*)p.mem0;
    for(int r = 0; r < RPWV; ++r){
        int row = row0 + r;
        size_t base = (size_t)row*128;
        float4 v0 = src[base + c0], v1 = src[base + c1];
        #pragma unroll
        for(int j = 0; j < CH; ++j){
            float w = p.wunW[(size_t)j*NN + row]*wnorm[j];
            v0.x = v0.x*(1.f - w*ev0[j].x) + w*av0[j].x;
            v0.y = v0.y*(1.f - w*ev0[j].y) + w*av0[j].y;
            v0.z = v0.z*(1.f - w*ev0[j].z) + w*av0[j].z;
            v0.w = v0.w*(1.f - w*ev0[j].w) + w*av0[j].w;
            v1.x = v1.x*(1.f - w*ev1[j].x) + w*av1[j].x;
            v1.y = v1.y*(1.f - w*ev1[j].y) + w*av1[j].y;
            v1.z = v1.z*(1.f - w*ev1[j].z) + w*av1[j].z;
            v1.w = v1.w*(1.f - w*ev1[j].w) + w*av1[j].w;
        }
        if constexpr(RP){
            float wr = p.wunR[(size_t)rstep*NN + row];   // RAW; normalized once in h-phase
            rpA.x += wr*v0.x; rpA.y += wr*v0.y; rpA.z += wr*v0.z; rpA.w += wr*v0.w;
            rpB.x += wr*v1.x; rpB.y += wr*v1.y; rpB.z += wr*v1.z; rpB.w += wr*v1.w;
        }
        if constexpr(UPD){
            float w = p.wunW[(size_t)CH*NN + row]*wnorm[CH];
            v0.x = v0.x*(1.f - w*ev0[CH].x) + w*av0[CH].x;
            v0.y = v0.y*(1.f - w*ev0[CH].y) + w*av0[CH].y;
            v0.z = v0.z*(1.f - w*ev0[CH].z) + w*av0[CH].z;
            v0.w = v0.w*(1.f - w*ev0[CH].w) + w*av0[CH].w;
            v1.x = v1.x*(1.f - w*ev1[CH].x) + w*av1[CH].x;
            v1.y = v1.y*(1.f - w*ev1[CH].y) + w*av1[CH].y;
            v1.z = v1.z*(1.f - w*ev1[CH].z) + w*av1[CH].z;
            v1.w = v1.w*(1.f - w*ev1[CH].w) + w*av1[CH].w;
        }
        if constexpr(DOTR || DOTW){
            float d = 0.f, dn = 0.f;
            float n = v0.x*v0.x+v0.y*v0.y+v0.z*v0.z+v0.w*v0.w
                    + v1.x*v1.x+v1.y*v1.y+v1.z*v1.z+v1.w*v1.w;
            if constexpr(DOTR)
                d = v0.x*kra.x+v0.y*kra.y+v0.z*kra.z+v0.w*kra.w
                  + v1.x*krb.x+v1.y*krb.y+v1.z*krb.z+v1.w*krb.w;
            if constexpr(DOTW)
                dn = v0.x*kwa.x+v0.y*kwa.y+v0.z*kwa.z+v0.w*kwa.w
                   + v1.x*kwb.x+v1.y*kwb.y+v1.z*kwb.z+v1.w*kwb.w;
            waveReduce3(d, dn, n);
            if(lane == 0){
                p.n2v[row] = n;
                float sn = sqrtf(n);
                if constexpr(DOTR){ p.dotR[row] = d;  zr += expf(betaR*d /(sn*knRv + EPSF)); }
                if constexpr(DOTW){ p.dotW[row] = dn; zw += expf(betaW*dn/(sn*knWv + EPSF)); }
            }
        }
    }
    if constexpr(DOTR || DOTW){
        if(lane == 0){ sm.zsh[wave][0] = zr; sm.zsh[wave][1] = zw; }
    }
    if constexpr(RP){
        ((float4*)(sm.big + wave*512))[c0] = rpA;
        ((float4*)(sm.big + wave*512))[c1] = rpB;
    }
    __syncthreads();
    if constexpr(RP){
        p.rp[(size_t)bid*512 + t] =
            sm.big[t] + sm.big[512+t] + sm.big[1024+t] + sm.big[1536+t];
        p.rp[(size_t)bid*512 + t + 256] =
            sm.big[t+256] + sm.big[768+t] + sm.big[1280+t] + sm.big[1792+t];
    }
    if(t == 0){
        if constexpr(DOTR) p.pZr[bid] = sm.zsh[0][0]+sm.zsh[1][0]+sm.zsh[2][0]+sm.zsh[3][0];
        if constexpr(DOTW) p.pZw[bid] = sm.zsh[0][1]+sm.zsh[1][1]+sm.zsh[2][1]+sm.zsh[3][1];
    }
    __syncthreads();
}

// ================= addressing-weight phase (one head) =================
__device__ __forceinline__ void whead_phase(const KP& p, Smem& sm,
    const float* sV, const float* dotv, const float* pZ,
    const float* wprev, const float* pSprev, int knidx,
    float* wun, float* pSout)
{
    int t = threadIdx.x, bid = blockIdx.x;
    float z = pZ[t] + pZ[t+256] + pZ[t+512] + pZ[t+768];
    float Z = blockReduce256(z, sm.red);
    float invSp = 1.f;
    if(pSprev){
        float sp = pSprev[t] + pSprev[t+256] + pSprev[t+512] + pSprev[t+768];
        invSp = 1.f/(blockReduce256(sp, sm.red) + EPSF);
    }
    float beta  = softplusf_(sV[0]);
    float g     = sigmoidf_(sV[1]);
    float s0 = sV[2], s1 = sV[3], s2 = sV[4];
    float smx = fmaxf(s0, fmaxf(s1, s2));
    float e0 = expf(s0-smx), e1 = expf(s1-smx), e2 = expf(s2-smx);
    float es = e0+e1+e2;
    s0 = e0/es; s1 = e1/es; s2 = e2/es;
    float gamma = 1.f + softplusf_(sV[5]);
    float knv = p.kn[knidx];
    float invZ = 1.f/Z;
    float wu = 0.f;
    if(t < ROWSB){
        int i = bid*ROWSB + t;
        int im = (i-1) & (NN-1), ip = (i+1) & (NN-1);
        auto wgf = [&](int j)->float{
            float a = beta*dotv[j]/(sqrtf(p.n2v[j])*knv + EPSF);
            float pv = wprev ? wprev[j]*invSp : (1.f/NN);
            return g*expf(a)*invZ + (1.f-g)*pv;
        };
        wu = powf(s0*wgf(im) + s1*wgf(i) + s2*wgf(ip), gamma);
        wun[i] = wu;
    }
    float S = blockReduce256(wu, sm.red);
    if(t == 0) pSout[bid] = S;
}

// ================= rp (1024x512) -> dst (64x512) =================
__device__ __forceinline__ void rsum1_phase(const KP& p, float* dst){
    int t = threadIdx.x, b = blockIdx.x;   // caller guards b<64
    float2 acc; acc.x = 0.f; acc.y = 0.f;
    const float2* r2 = (const float2*)p.rp;
    for(int j = 0; j < 16; ++j){
        float2 v = r2[(size_t)(b*16 + j)*256 + t];
        acc.x += v.x; acc.y += v.y;
    }
    ((float2*)dst)[b*256 + t] = acc;
}

// ================= h = relu(W1 @ [cont, r]) for 25 outputs =================
__device__ __forceinline__ void h_phase(const KP& p, Smem& sm, int hb, int step,
                                        const float* p2src){
    int t = threadIdx.x;
    const float* pS = p.pSR + step*GRIDB;
    float sp = pS[t] + pS[t+256] + pS[t+512] + pS[t+768];
    float invS = 1.f/(blockReduce256(sp, sm.red) + EPSF);
    float2 acc; acc.x = 0.f; acc.y = 0.f;
    const float2* q = (const float2*)p2src;
    for(int j = 0; j < 64; ++j){
        float2 v = q[j*256 + t];
        acc.x += v.x; acc.y += v.y;
    }
    float* conc = sm.big;                // 640 floats
    conc[128 + 2*t]     = acc.x*invS;
    conc[128 + 2*t + 1] = acc.y*invS;
    if(t < 128) conc[t] = p.cont[step*128 + t];
    __syncthreads();
    int wave = t >> 6, lane = t & 63;
    for(int ol = wave; ol < 25; ol += 4){
        int o = hb*25 + ol;
        const float* wr = p.W1 + (size_t)o*640;
        float a = 0.f;
        for(int q2 = lane; q2 < 640; q2 += 64) a += wr[q2]*conc[q2];
        waveReduce1(a);
        if(lane == 0) p.hbuf[step*200 + o] = fmaxf(a + p.b1[o], 0.f);
    }
    __syncthreads();
}

// ================= out = W2 @ h + b2 =================
__device__ __forceinline__ void out_phase(const KP& p, int step){
    int t = threadIdx.x;
    if(t < 10){
        float a = p.b2[t];
        const float* wr = p.W2 + t*200;
        const float* h = p.hbuf + step*200;
        for(int j = 0; j < 200; ++j) a += wr[j]*h[j];
        p.out[step*10 + t] = a;
    }
}

// ================= cooperative all-in-one =================
__global__ void __launch_bounds__(256, 4) k_coop(KP p){
    cg::grid_group g = cg::this_grid();
    __shared__ Smem sm;
    int bid = blockIdx.x;
    // A: dots kW0 + n2 on mem0
    sweep_phase<0,false,false,false,true>(p, sm, 0, nullptr,nullptr,0, p.kW, p.sW, 0);
    g.sync();
    // B: w_w(0)
    whead_phase(p, sm, p.sW, p.dotW, p.pZw, nullptr, nullptr, 0, p.wunW, p.pSW);
    g.sync();
    // C0: apply write0 -> M0, dots kR0 + kW1
    sweep_phase<0,false,true,true,true>(p, sm, 0, p.kR, p.sR, 1, p.kW+512, p.sW+8, 2);
    g.sync();
    // D0: w_r(0), w_w(1)
    whead_phase(p, sm, p.sR, p.dotR, p.pZr, nullptr, nullptr, 1, p.wunR, p.pSR);
    whead_phase(p, sm, p.sW+8, p.dotW, p.pZw, p.wunW, p.pSW, 2, p.wunW+NN, p.pSW+GRIDB);
    g.sync();
    // C1: M0, r(0) partials, write1 -> M1, dots kR1 + kW2
    sweep_phase<1,true,true,true,true>(p, sm, 0, p.kR+512, p.sR+8, 3, p.kW+1024, p.sW+16, 4);
    g.sync();
    // D1: w_r(1), w_w(2), rsum r(0)->p2[0]
    whead_phase(p, sm, p.sR+8, p.dotR, p.pZr, p.wunR, p.pSR, 3, p.wunR+NN, p.pSR+GRIDB);
    whead_phase(p, sm, p.sW+16, p.dotW, p.pZw, p.wunW+NN, p.pSW+GRIDB, 4,
                p.wunW+2*(size_t)NN, p.pSW+2*GRIDB);
    if(bid < 64) rsum1_phase(p, p.p2);
    g.sync();
    // C2: M1, r(1) partials, write2 -> M2, dots kR2 + kW3
    sweep_phase<2,true,true,true,true>(p, sm, 1, p.kR+1024, p.sR+16, 5, p.kW+1536, p.sW+24, 6);
    g.sync();
    // D2: w_r(2), w_w(3), rsum r(1)->p2[1], h(0)
    whead_phase(p, sm, p.sR+16, p.dotR, p.pZr, p.wunR+NN, p.pSR+GRIDB, 5,
                p.wunR+2*(size_t)NN, p.pSR+2*GRIDB);
    whead_phase(p, sm, p.sW+24, p.dotW, p.pZw, p.wunW+2*(size_t)NN, p.pSW+2*GRIDB, 6,
                p.wunW+3*(size_t)NN, p.pSW+3*GRIDB);
    if(bid < 64) rsum1_phase(p, p.p2 + 64*512);
    if(bid >= 64 && bid < 72) h_phase(p, sm, bid-64, 0, p.p2);
    g.sync();
    // C3: M2, r(2) partials, write3 -> M3, dots kR3
    sweep_phase<3,true,true,true,false>(p, sm, 2, p.kR+1536, p.sR+24, 7, nullptr,nullptr,0);
    g.sync();
    // D3: w_r(3), rsum r(2)->p2[0], h(1), out(0)
    whead_phase(p, sm, p.sR+24, p.dotR, p.pZr, p.wunR+2*(size_t)NN, p.pSR+2*GRIDB, 7,
                p.wunR+3*(size_t)NN, p.pSR+3*GRIDB);
    if(bid < 64) rsum1_phase(p, p.p2);
    if(bid >= 64 && bid < 72) h_phase(p, sm, bid-64, 1, p.p2 + 64*512);
    if(bid == 72) out_phase(p, 0);
    g.sync();
    // C4: M3, r(3) partials
    sweep_phase<4,true,false,false,false>(p, sm, 3, nullptr,nullptr,0, nullptr,nullptr,0);
    g.sync();
    // D4: rsum r(3)->p2[1], h(2), out(1)
    if(bid < 64) rsum1_phase(p, p.p2 + 64*512);
    if(bid >= 64 && bid < 72) h_phase(p, sm, bid-64, 2, p.p2);
    if(bid == 72) out_phase(p, 1);
    g.sync();
    // E5: h(3), out(2)
    if(bid < 8) h_phase(p, sm, bid, 3, p.p2 + 64*512);
    if(bid == 8) out_phase(p, 2);
    g.sync();
    // E6: out(3)
    if(bid == 0) out_phase(p, 3);
}

// ================= fallback wrappers (same math, separate launches) ========
__global__ void __launch_bounds__(256) g_sweepA(KP p){
    __shared__ Smem sm;
    sweep_phase<0,false,false,false,true>(p, sm, 0, nullptr,nullptr,0, p.kW, p.sW, 0);
}
__global__ void __launch_bounds__(256) g_sweepC0(KP p){
    __shared__ Smem sm;
    sweep_phase<0,false,true,true,true>(p, sm, 0, p.kR, p.sR, 1, p.kW+512, p.sW+8, 2);
}
__global__ void __launch_bounds__(256) g_sweepC1(KP p){
    __shared__ Smem sm;
    sweep_phase<1,true,true,true,true>(p, sm, 0, p.kR+512, p.sR+8, 3, p.kW+1024, p.sW+16, 4);
}
__global__ void __launch_bounds__(256) g_sweepC2(KP p){
    __shared__ Smem sm;
    sweep_phase<2,true,true,true,true>(p, sm, 1, p.kR+1024, p.sR+16, 5, p.kW+1536, p.sW+24, 6);
}
__global__ void __launch_bounds__(256) g_sweepC3(KP p){
    __shared__ Smem sm;
    sweep_phase<3,true,true,true,false>(p, sm, 2, p.kR+1536, p.sR+24, 7, nullptr,nullptr,0);
}
__global__ void __launch_bounds__(256) g_sweepC4(KP p){
    __shared__ Smem sm;
    sweep_phase<4,true,false,false,false>(p, sm, 3, nullptr,nullptr,0, nullptr,nullptr,0);
}
__global__ void __launch_bounds__(256) g_whead(KP p, const float* sV, const float* dotv,
    const float* pZ, const float* wprev, const float* pSprev, int knidx,
    float* wun, float* pSout){
    __shared__ Smem sm;
    whead_phase(p, sm, sV, dotv, pZ, wprev, pSprev, knidx, wun, pSout);
}
__global__ void __launch_bounds__(256) g_rsum1(KP p, float* dst){
    rsum1_phase(p, dst);
}
__global__ void __launch_bounds__(256) g_h(KP p, int step, const float* p2src){
    __shared__ Smem sm;
    h_phase(p, sm, blockIdx.x, step, p2src);
}
__global__ void __launch_bounds__(256) g_out(KP p, int step){
    out_phase(p, step);
}

// ================= controller prep (unchanged from round 5) =================
__global__ void k_owor(const float* __restrict__ x, const float* __restrict__ Wc,
                       const float* __restrict__ bc,
                       const float* __restrict__ Ww, const float* __restrict__ bw,
                       const float* __restrict__ Wr, const float* __restrict__ br,
                       float* __restrict__ cont,
                       float* __restrict__ kW, float* __restrict__ sW,
                       float* __restrict__ eW, float* __restrict__ aW,
                       float* __restrict__ kR, float* __restrict__ sR){
    __shared__ float cs[512];
    int tid = threadIdx.x;
    for(int q = tid; q < 512; q += 256){
        int t = q >> 7, c = q & 127;
        float acc = bc[c];
        const float* xr = x + t*CTRLD;
        const float* wr = Wc + c*CTRLD;
        for(int d = 0; d < CTRLD; ++d) acc += xr[d]*wr[d];
        cs[q] = acc;
        if(blockIdx.x == 0) cont[q] = acc;
    }
    __syncthreads();
    int idx = blockIdx.x*256 + tid;
    if(idx < 4*WLEN){
        int t = idx / WLEN, o = idx % WLEN;
        float acc = bw[o];
        const float* cr = cs + t*CTRLD;
        const float* wr = Ww + o*CTRLD;
        for(int d = 0; d < CTRLD; ++d) acc += cr[d]*wr[d];
        if(o < 512)       kW[t*512 + o] = acc;
        else if(o < 518)  sW[t*8 + (o-512)] = acc;
        else if(o < 1030) eW[t*512 + (o-518)] = sigmoidf_(acc);
        else              aW[t*512 + (o-1030)] = acc;
    } else {
        int j = idx - 4*WLEN;
        if(j < 4*RLEN){
            int t = j / RLEN, o = j % RLEN;
            float acc = br[o];
            const float* cr = cs + t*CTRLD;
            const float* wr = Wr + o*CTRLD;
            for(int d = 0; d < CTRLD; ++d) acc += cr[d]*wr[d];
            if(o < 512) kR[t*512 + o] = acc;
            else        sR[t*8 + (o-512)] = acc;
        }
    }
}

__global__ void k_prep(const float* __restrict__ kW, const float* __restrict__ kR,
                       float* __restrict__ kn){
    int t = threadIdx.x;            // 512 threads = 8 waves
    int wave = t >> 6, lane = t & 63;
    int step = wave >> 1, which = wave & 1;
    const float* base = which ? (kR + step*512) : (kW + step*512);
    float s = 0.f;
    for(int h = 0; h < 8; ++h){ float v = base[lane + h*64]; s += v*v; }
    waveReduce1(s);
    if(lane == 0) kn[wave] = sqrtf(s);
}

extern "C" void kernel_launch(void* const* d_in, const int* in_sizes, int n_in,
                              void* d_out, int out_size, void* d_ws, size_t ws_size,
                              hipStream_t stream) {
    const float* x    = (const float*)d_in[0];
    const float* mem0 = (const float*)d_in[1];
    const float* Wc   = (const float*)d_in[2];
    const float* bc   = (const float*)d_in[3];
    const float* Wr   = (const float*)d_in[4];
    const float* br   = (const float*)d_in[5];
    const float* Ww   = (const float*)d_in[6];
    const float* bw   = (const float*)d_in[7];
    const float* W1   = (const float*)d_in[8];
    const float* b1   = (const float*)d_in[9];
    const float* W2   = (const float*)d_in[10];
    const float* b2   = (const float*)d_in[11];

    float* ws = (float*)d_ws;
    size_t off = 0;
    float* wunW = ws + off; off += 4*(size_t)NN;
    float* pSW  = ws + off; off += 4*GRIDB;
    float* wunR = ws + off; off += 4*(size_t)NN;
    float* pSR  = ws + off; off += 4*GRIDB;
    float* dotR = ws + off; off += NN;
    float* dotW = ws + off; off += NN;
    float* n2v  = ws + off; off += NN;
    float* pZr  = ws + off; off += GRIDB;
    float* pZw  = ws + off; off += GRIDB;
    float* cont = ws + off; off += 512;
    float* kW   = ws + off; off += 4*512;
    float* sW   = ws + off; off += 4*8;
    float* eW   = ws + off; off += 4*512;
    float* aW   = ws + off; off += 4*512;
    float* kR   = ws + off; off += 4*512;
    float* sR   = ws + off; off += 4*8;
    float* kn   = ws + off; off += 16;
    float* rp   = ws + off; off += (size_t)GRIDB*512;
    float* p2   = ws + off; off += 2*64*512;
    float* hbuf = ws + off; off += 1024;

    KP P;
    P.mem0 = mem0; P.cont = cont;
    P.kW = kW; P.sW = sW; P.eW = eW; P.aW = aW; P.kR = kR; P.sR = sR; P.kn = kn;
    P.dotR = dotR; P.dotW = dotW; P.n2v = n2v;
    P.wunW = wunW; P.pSW = pSW; P.wunR = wunR; P.pSR = pSR;
    P.pZr = pZr; P.pZw = pZw;
    P.rp = rp; P.p2 = p2; P.hbuf = hbuf;
    P.W1 = W1; P.b1 = b1; P.W2 = W2; P.b2 = b2;
    P.out = (float*)d_out;

    k_owor<<<33, 256, 0, stream>>>(x, Wc, bc, Ww, bw, Wr, br,
                                   cont, kW, sW, eW, aW, kR, sR);
    k_prep<<<1, 512, 0, stream>>>(kW, kR, kn);

    // ---- cooperative path with safe fallback ----
    bool useCoop = false;
    int coopAttr = 0;
    if(hipDeviceGetAttribute(&coopAttr, hipDeviceAttributeCooperativeLaunch, 0) == hipSuccess
       && coopAttr){
        int nCU = 0, maxb = 0;
        if(hipDeviceGetAttribute(&nCU, hipDeviceAttributeMultiprocessorCount, 0) == hipSuccess
           && hipOccupancyMaxActiveBlocksPerMultiprocessor(&maxb, k_coop, 256, 0) == hipSuccess
           && (long)maxb*(long)nCU >= GRIDB){
            useCoop = true;
        }
    }
    if(useCoop){
        void* args[] = { (void*)&P };
        hipError_t e = hipLaunchCooperativeKernel((const void*)k_coop,
                           dim3(GRIDB), dim3(256), args, 0, stream);
        if(e != hipSuccess){ (void)hipGetLastError(); useCoop = false; }
    }
    if(!useCoop){
        g_sweepA<<<GRIDB, 256, 0, stream>>>(P);
        g_whead <<<GRIDB, 256, 0, stream>>>(P, sW, dotW, pZw, nullptr, nullptr, 0, wunW, pSW);
        g_sweepC0<<<GRIDB, 256, 0, stream>>>(P);
        g_whead <<<GRIDB, 256, 0, stream>>>(P, sR, dotR, pZr, nullptr, nullptr, 1, wunR, pSR);
        g_whead <<<GRIDB, 256, 0, stream>>>(P, sW+8, dotW, pZw, wunW, pSW, 2, wunW+NN, pSW+GRIDB);
        g_sweepC1<<<GRIDB, 256, 0, stream>>>(P);
        g_whead <<<GRIDB, 256, 0, stream>>>(P, sR+8, dotR, pZr, wunR, pSR, 3, wunR+NN, pSR+GRIDB);
        g_whead <<<GRIDB, 256, 0, stream>>>(P, sW+16, dotW, pZw, wunW+NN, pSW+GRIDB, 4,
                                            wunW+2*(size_t)NN, pSW+2*GRIDB);
        g_rsum1 <<<64, 256, 0, stream>>>(P, p2);
        g_sweepC2<<<GRIDB, 256, 0, stream>>>(P);
        g_whead <<<GRIDB, 256, 0, stream>>>(P, sR+16, dotR, pZr, wunR+NN, pSR+GRIDB, 5,
                                            wunR+2*(size_t)NN, pSR+2*GRIDB);
        g_whead <<<GRIDB, 256, 0, stream>>>(P, sW+24, dotW, pZw, wunW+2*(size_t)NN, pSW+2*GRIDB, 6,
                                            wunW+3*(size_t)NN, pSW+3*GRIDB);
        g_rsum1 <<<64, 256, 0, stream>>>(P, p2 + 64*512);
        g_h     <<<8, 256, 0, stream>>>(P, 0, p2);
        g_sweepC3<<<GRIDB, 256, 0, stream>>>(P);
        g_whead <<<GRIDB, 256, 0, stream>>>(P, sR+24, dotR, pZr, wunR+2*(size_t)NN, pSR+2*GRIDB, 7,
                                            wunR+3*(size_t)NN, pSR+3*GRIDB);
        g_rsum1 <<<64, 256, 0, stream>>>(P, p2);
        g_h     <<<8, 256, 0, stream>>>(P, 1, p2 + 64*512);
        g_out   <<<1, 256, 0, stream>>>(P, 0);
        g_sweepC4<<<GRIDB, 256, 0, stream>>>(P);
        g_rsum1 <<<64, 256, 0, stream>>>(P, p2 + 64*512);
        g_h     <<<8, 256, 0, stream>>>(P, 2, p2);
        g_out   <<<1, 256, 0, stream>>>(P, 1);
        g_h     <<<8, 256, 0, stream>>>(P, 3, p2 + 64*512);
        g_out   <<<1, 256, 0, stream>>>(P, 2);
        g_out   <<<1, 256, 0, stream>>>(P, 3);
    }
    (void)in_sizes; (void)n_in; (void)out_size; (void)ws_size;
}

// Round 7
// 375.803 us; speedup vs baseline: 1.7158x; 1.0460x over previous
//
#include <hip/hip_runtime.h>
#include <hip/hip_cooperative_groups.h>
#include <hip/hip_fp16.h>
#include <math.h>

namespace cg = cooperative_groups;

#define NN    65536
#define CTRLD 128
#define WLEN  1542
#define RLEN  518
#define EPSF  1e-16f
#define GRIDB 1024
#define ROWSB 64     // rows per block
#define RPWV  16     // rows per wave

struct KP {
  const float* mem0; const float* cont;
  float* mem16;                       // fp16 shadow of mem0 (written by sweep A)
  const float* kW; const float* sW; const float* eW; const float* aW;
  const float* kR; const float* sR; float* kn;
  float *dotR, *dotW, *n2v;
  float *wunW, *pSW, *wunR, *pSR;
  float *pZr, *pZw;
  float *rp, *p2, *hbuf;
  const float *W1, *b1, *W2, *b2;
  float* out;
  // owor inputs (for fused P0)
  const float *x, *Wc, *bc, *Ww, *bw, *Wr, *br;
  float *contw, *kWw, *sWw, *eWw, *aWw, *kRw, *sRw;
};

struct Smem { float red[256]; float big[2048]; float zsh[4][2]; };

__device__ __forceinline__ float softplusf_(float x){
    return x > 0.f ? x + log1pf(expf(-x)) : log1pf(expf(x));
}
__device__ __forceinline__ float sigmoidf_(float x){ return 1.f/(1.f+expf(-x)); }
__device__ __forceinline__ float dot4_(const float4& a, const float4& b){
    return a.x*b.x + a.y*b.y + a.z*b.z + a.w*b.w;
}

__device__ __forceinline__ float blockReduce256(float v, float* red){
    int t = threadIdx.x;
    red[t] = v; __syncthreads();
    for(int s = 128; s; s >>= 1){ if(t < s) red[t] += red[t+s]; __syncthreads(); }
    float r = red[0]; __syncthreads();
    return r;
}
__device__ __forceinline__ void waveReduce3(float& a, float& b, float& c){
    for(int o = 32; o; o >>= 1){
        a += __shfl_down(a,o); b += __shfl_down(b,o); c += __shfl_down(c,o);
    }
}
__device__ __forceinline__ void waveReduce1(float& a){
    for(int o = 32; o; o >>= 1) a += __shfl_down(a,o);
}

// ================= owor phase (blocks 0..32) =================
__device__ __forceinline__ void owor_phase(const KP& p, Smem& sm, int bid){
    float* cs = sm.big;
    int tid = threadIdx.x;
    for(int q = tid; q < 512; q += 256){
        int t = q >> 7, c = q & 127;
        float acc = p.bc[c];
        const float* xr = p.x + t*CTRLD;
        const float* wr = p.Wc + c*CTRLD;
        for(int d = 0; d < CTRLD; ++d) acc += xr[d]*wr[d];
        cs[q] = acc;
        if(bid == 0) p.contw[q] = acc;
    }
    __syncthreads();
    int idx = bid*256 + tid;
    if(idx < 4*WLEN){
        int t = idx / WLEN, o = idx % WLEN;
        float acc = p.bw[o];
        const float* cr = cs + t*CTRLD;
        const float* wr = p.Ww + o*CTRLD;
        for(int d = 0; d < CTRLD; ++d) acc += cr[d]*wr[d];
        if(o < 512)       p.kWw[t*512 + o] = acc;
        else if(o < 518)  p.sWw[t*8 + (o-512)] = acc;
        else if(o < 1030) p.eWw[t*512 + (o-518)] = sigmoidf_(acc);
        else              p.aWw[t*512 + (o-1030)] = acc;
    } else {
        int j = idx - 4*WLEN;
        if(j < 4*RLEN){
            int t = j / RLEN, o = j % RLEN;
            float acc = p.br[o];
            const float* cr = cs + t*CTRLD;
            const float* wr = p.Wr + o*CTRLD;
            for(int d = 0; d < CTRLD; ++d) acc += cr[d]*wr[d];
            if(o < 512) p.kRw[t*512 + o] = acc;
            else        p.sRw[t*8 + (o-512)] = acc;
        }
    }
    __syncthreads();
}

// ================= sweep phase =================
// CVT: read fp32 mem0, write fp16 shadow. else read fp16 shadow.
// CH chained writes -> M_{CH-1}; RP: r partials (RAW wunR[rstep]); UPD: apply
// write CH; DOTR/DOTW: dots vs kRc/kWn + exp partials + publish key norms.
template<int CH, bool RP, bool UPD, bool DOTR, bool DOTW, bool CVT>
__device__ __forceinline__ void sweep_phase(const KP& p, Smem& sm, int rstep,
    const float* kRc, const float* sRc, int knRi,
    const float* kWn, const float* sWn, int knWi)
{
    constexpr int NW = CH + (UPD ? 1 : 0);
    constexpr int NA = (NW > 0) ? NW : 1;
    int t = threadIdx.x, bid = blockIdx.x;
    float wnorm[NA];
    #pragma unroll
    for(int j = 0; j < NW; ++j){
        float s = p.pSW[j*GRIDB+t] + p.pSW[j*GRIDB+t+256]
                + p.pSW[j*GRIDB+t+512] + p.pSW[j*GRIDB+t+768];
        wnorm[j] = 1.f/(blockReduce256(s, sm.red) + EPSF);
    }
    int wave = t >> 6, lane = t & 63;
    int c0 = 2*lane, c1 = 2*lane + 1;     // contiguous 8 floats per thread
    float4 ev0[NA], ev1[NA], av0[NA], av1[NA];
    #pragma unroll
    for(int j = 0; j < NW; ++j){
        ev0[j] = ((const float4*)(p.eW + j*512))[c0];
        ev1[j] = ((const float4*)(p.eW + j*512))[c1];
        av0[j] = ((const float4*)(p.aW + j*512))[c0];
        av1[j] = ((const float4*)(p.aW + j*512))[c1];
    }
    float4 kra, krb, kwa, kwb;
    float betaR = 0.f, betaW = 0.f, knRv = 1.f, knWv = 1.f;
    if constexpr(DOTR){
        kra = ((const float4*)kRc)[c0]; krb = ((const float4*)kRc)[c1];
        betaR = softplusf_(sRc[0]);
        float n2 = blockReduce256(dot4_(kra,kra) + dot4_(krb,krb), sm.red);
        knRv = sqrtf(n2*0.25f);           // lanes repeat 4x across waves
        if(t == 0 && bid == 0) p.kn[knRi] = knRv;
    }
    if constexpr(DOTW){
        kwa = ((const float4*)kWn)[c0]; kwb = ((const float4*)kWn)[c1];
        betaW = softplusf_(sWn[0]);
        float n2 = blockReduce256(dot4_(kwa,kwa) + dot4_(kwb,kwb), sm.red);
        knWv = sqrtf(n2*0.25f);
        if(t == 0 && bid == 0) p.kn[knWi] = knWv;
    }
    float4 rpA = {0,0,0,0}, rpB = {0,0,0,0};
    float zr = 0.f, zw = 0.f;
    int row0 = bid*ROWSB + wave*RPWV;
    for(int r = 0; r < RPWV; ++r){
        int row = row0 + r;
        float4 v0, v1;
        if constexpr(CVT){
            const float4* src = (const float4*)p.mem0;
            v0 = src[(size_t)row*128 + c0];
            v1 = src[(size_t)row*128 + c1];
        } else {
            float4 raw = ((const float4*)p.mem16)[(size_t)row*64 + lane];
            const __half2* hp = (const __half2*)&raw;
            float2 f0 = __half22float2(hp[0]);
            float2 f1 = __half22float2(hp[1]);
            float2 f2 = __half22float2(hp[2]);
            float2 f3 = __half22float2(hp[3]);
            v0 = make_float4(f0.x, f0.y, f1.x, f1.y);
            v1 = make_float4(f2.x, f2.y, f3.x, f3.y);
        }
        #pragma unroll
        for(int j = 0; j < CH; ++j){
            float w = p.wunW[(size_t)j*NN + row]*wnorm[j];
            v0.x = fmaf(w, fmaf(-ev0[j].x, v0.x, av0[j].x), v0.x);
            v0.y = fmaf(w, fmaf(-ev0[j].y, v0.y, av0[j].y), v0.y);
            v0.z = fmaf(w, fmaf(-ev0[j].z, v0.z, av0[j].z), v0.z);
            v0.w = fmaf(w, fmaf(-ev0[j].w, v0.w, av0[j].w), v0.w);
            v1.x = fmaf(w, fmaf(-ev1[j].x, v1.x, av1[j].x), v1.x);
            v1.y = fmaf(w, fmaf(-ev1[j].y, v1.y, av1[j].y), v1.y);
            v1.z = fmaf(w, fmaf(-ev1[j].z, v1.z, av1[j].z), v1.z);
            v1.w = fmaf(w, fmaf(-ev1[j].w, v1.w, av1[j].w), v1.w);
        }
        if constexpr(RP){
            float wr = p.wunR[(size_t)rstep*NN + row];   // RAW; one normalize at h
            rpA.x += wr*v0.x; rpA.y += wr*v0.y; rpA.z += wr*v0.z; rpA.w += wr*v0.w;
            rpB.x += wr*v1.x; rpB.y += wr*v1.y; rpB.z += wr*v1.z; rpB.w += wr*v1.w;
        }
        if constexpr(UPD){
            float w = p.wunW[(size_t)CH*NN + row]*wnorm[CH];
            v0.x = fmaf(w, fmaf(-ev0[CH].x, v0.x, av0[CH].x), v0.x);
            v0.y = fmaf(w, fmaf(-ev0[CH].y, v0.y, av0[CH].y), v0.y);
            v0.z = fmaf(w, fmaf(-ev0[CH].z, v0.z, av0[CH].z), v0.z);
            v0.w = fmaf(w, fmaf(-ev0[CH].w, v0.w, av0[CH].w), v0.w);
            v1.x = fmaf(w, fmaf(-ev1[CH].x, v1.x, av1[CH].x), v1.x);
            v1.y = fmaf(w, fmaf(-ev1[CH].y, v1.y, av1[CH].y), v1.y);
            v1.z = fmaf(w, fmaf(-ev1[CH].z, v1.z, av1[CH].z), v1.z);
            v1.w = fmaf(w, fmaf(-ev1[CH].w, v1.w, av1[CH].w), v1.w);
        }
        if constexpr(CVT){
            float4 packed;
            __half2* op = (__half2*)&packed;
            op[0] = __floats2half2_rn(v0.x, v0.y);
            op[1] = __floats2half2_rn(v0.z, v0.w);
            op[2] = __floats2half2_rn(v1.x, v1.y);
            op[3] = __floats2half2_rn(v1.z, v1.w);
            ((float4*)p.mem16)[(size_t)row*64 + lane] = packed;
        }
        if constexpr(DOTR || DOTW){
            float d = 0.f, dn = 0.f;
            float n = dot4_(v0,v0) + dot4_(v1,v1);
            if constexpr(DOTR) d  = dot4_(v0,kra) + dot4_(v1,krb);
            if constexpr(DOTW) dn = dot4_(v0,kwa) + dot4_(v1,kwb);
            waveReduce3(d, dn, n);
            if(lane == 0){
                p.n2v[row] = n;
                float sn = sqrtf(n);
                if constexpr(DOTR){ p.dotR[row] = d;  zr += expf(betaR*d /(sn*knRv + EPSF)); }
                if constexpr(DOTW){ p.dotW[row] = dn; zw += expf(betaW*dn/(sn*knWv + EPSF)); }
            }
        }
    }
    if constexpr(DOTR || DOTW){
        if(lane == 0){ sm.zsh[wave][0] = zr; sm.zsh[wave][1] = zw; }
    }
    if constexpr(RP){
        ((float4*)(sm.big + wave*512))[c0] = rpA;
        ((float4*)(sm.big + wave*512))[c1] = rpB;
    }
    __syncthreads();
    if constexpr(RP){
        p.rp[(size_t)bid*512 + t] =
            sm.big[t] + sm.big[512+t] + sm.big[1024+t] + sm.big[1536+t];
        p.rp[(size_t)bid*512 + t + 256] =
            sm.big[t+256] + sm.big[768+t] + sm.big[1280+t] + sm.big[1792+t];
    }
    if(t == 0){
        if constexpr(DOTR) p.pZr[bid] = sm.zsh[0][0]+sm.zsh[1][0]+sm.zsh[2][0]+sm.zsh[3][0];
        if constexpr(DOTW) p.pZw[bid] = sm.zsh[0][1]+sm.zsh[1][1]+sm.zsh[2][1]+sm.zsh[3][1];
    }
    __syncthreads();
}

// ================= addressing-weight phase (one head) =================
__device__ __forceinline__ void whead_phase(const KP& p, Smem& sm,
    const float* sV, const float* dotv, const float* pZ,
    const float* wprev, const float* pSprev, int knidx,
    float* wun, float* pSout)
{
    int t = threadIdx.x, bid = blockIdx.x;
    float z = pZ[t] + pZ[t+256] + pZ[t+512] + pZ[t+768];
    float Z = blockReduce256(z, sm.red);
    float invSp = 1.f;
    if(pSprev){
        float sp = pSprev[t] + pSprev[t+256] + pSprev[t+512] + pSprev[t+768];
        invSp = 1.f/(blockReduce256(sp, sm.red) + EPSF);
    }
    float beta  = softplusf_(sV[0]);
    float g     = sigmoidf_(sV[1]);
    float s0 = sV[2], s1 = sV[3], s2 = sV[4];
    float smx = fmaxf(s0, fmaxf(s1, s2));
    float e0 = expf(s0-smx), e1 = expf(s1-smx), e2 = expf(s2-smx);
    float es = e0+e1+e2;
    s0 = e0/es; s1 = e1/es; s2 = e2/es;
    float gamma = 1.f + softplusf_(sV[5]);
    float knv = p.kn[knidx];
    float invZ = 1.f/Z;
    float wu = 0.f;
    if(t < ROWSB){
        int i = bid*ROWSB + t;
        int im = (i-1) & (NN-1), ip = (i+1) & (NN-1);
        auto wgf = [&](int j)->float{
            float a = beta*dotv[j]/(sqrtf(p.n2v[j])*knv + EPSF);
            float pv = wprev ? wprev[j]*invSp : (1.f/NN);
            return g*expf(a)*invZ + (1.f-g)*pv;
        };
        wu = powf(s0*wgf(im) + s1*wgf(i) + s2*wgf(ip), gamma);
        wun[i] = wu;
    }
    float S = blockReduce256(wu, sm.red);
    if(t == 0) pSout[bid] = S;
}

// ================= rp (1024x512) -> dst (64x512) =================
__device__ __forceinline__ void rsum1_phase(const KP& p, float* dst){
    int t = threadIdx.x, b = blockIdx.x;   // caller guards b<64
    float2 acc; acc.x = 0.f; acc.y = 0.f;
    const float2* r2 = (const float2*)p.rp;
    for(int j = 0; j < 16; ++j){
        float2 v = r2[(size_t)(b*16 + j)*256 + t];
        acc.x += v.x; acc.y += v.y;
    }
    ((float2*)dst)[b*256 + t] = acc;
}

// ================= h = relu(W1 @ [cont, r]) : 8-block variant =================
__device__ __forceinline__ void h_phase(const KP& p, Smem& sm, int hb, int step,
                                        const float* p2src){
    int t = threadIdx.x;
    const float* pS = p.pSR + step*GRIDB;
    float sp = pS[t] + pS[t+256] + pS[t+512] + pS[t+768];
    float invS = 1.f/(blockReduce256(sp, sm.red) + EPSF);
    float2 acc; acc.x = 0.f; acc.y = 0.f;
    const float2* q = (const float2*)p2src;
    for(int j = 0; j < 64; ++j){
        float2 v = q[j*256 + t];
        acc.x += v.x; acc.y += v.y;
    }
    float* conc = sm.big;                // 640 floats
    conc[128 + 2*t]     = acc.x*invS;
    conc[128 + 2*t + 1] = acc.y*invS;
    if(t < 128) conc[t] = p.cont[step*128 + t];
    __syncthreads();
    int wave = t >> 6, lane = t & 63;
    for(int ol = wave; ol < 25; ol += 4){
        int o = hb*25 + ol;
        const float* wr = p.W1 + (size_t)o*640;
        float a = 0.f;
        for(int q2 = lane; q2 < 640; q2 += 64) a += wr[q2]*conc[q2];
        waveReduce1(a);
        if(lane == 0) p.hbuf[step*200 + o] = fmaxf(a + p.b1[o], 0.f);
    }
    __syncthreads();
}

// ================= out = W2 @ h + b2 =================
__device__ __forceinline__ void out_phase(const KP& p, int step){
    int t = threadIdx.x;
    if(t < 10){
        float a = p.b2[t];
        const float* wr = p.W2 + t*200;
        const float* h = p.hbuf + step*200;
        for(int j = 0; j < 200; ++j) a += wr[j]*h[j];
        p.out[step*10 + t] = a;
    }
}

// ================= single-block h + out (tail) =================
__device__ __forceinline__ void hfull_phase(const KP& p, Smem& sm, int step,
                                            const float* p2src){
    int t = threadIdx.x;
    const float* pS = p.pSR + step*GRIDB;
    float sp = pS[t] + pS[t+256] + pS[t+512] + pS[t+768];
    float invS = 1.f/(blockReduce256(sp, sm.red) + EPSF);
    float2 acc; acc.x = 0.f; acc.y = 0.f;
    const float2* q = (const float2*)p2src;
    for(int j = 0; j < 64; ++j){
        float2 v = q[j*256 + t];
        acc.x += v.x; acc.y += v.y;
    }
    float* conc = sm.big;
    conc[128 + 2*t]     = acc.x*invS;
    conc[128 + 2*t + 1] = acc.y*invS;
    if(t < 128) conc[t] = p.cont[step*128 + t];
    __syncthreads();
    int wave = t >> 6, lane = t & 63;
    float* hsh = sm.big + 1024;          // 200 floats
    for(int o = wave; o < 200; o += 4){
        const float* wr = p.W1 + (size_t)o*640;
        float a = 0.f;
        for(int q2 = lane; q2 < 640; q2 += 64) a += wr[q2]*conc[q2];
        waveReduce1(a);
        if(lane == 0) hsh[o] = fmaxf(a + p.b1[o], 0.f);
    }
    __syncthreads();
    if(t < 10){
        float a = p.b2[t];
        const float* wr = p.W2 + t*200;
        for(int j = 0; j < 200; ++j) a += wr[j]*hsh[j];
        p.out[step*10 + t] = a;
    }
}

// ================= cooperative all-in-one =================
__global__ void __launch_bounds__(256, 4) k_coop(KP p){
    cg::grid_group g = cg::this_grid();
    __shared__ Smem sm;
    int bid = blockIdx.x;
    // P0: controller outputs
    if(bid < 33) owor_phase(p, sm, bid);
    g.sync();
    // A: dots kW0 + n2 on fp32 mem0; write fp16 shadow
    sweep_phase<0,false,false,false,true,true>(p, sm, 0, nullptr,nullptr,0, p.kW, p.sW, 0);
    g.sync();
    // B: w_w(0)
    whead_phase(p, sm, p.sW, p.dotW, p.pZw, nullptr, nullptr, 0, p.wunW, p.pSW);
    g.sync();
    // C0: apply write0 -> M0, dots kR0 + kW1
    sweep_phase<0,false,true,true,true,false>(p, sm, 0, p.kR, p.sR, 1, p.kW+512, p.sW+8, 2);
    g.sync();
    // D0: w_r(0), w_w(1)
    whead_phase(p, sm, p.sR, p.dotR, p.pZr, nullptr, nullptr, 1, p.wunR, p.pSR);
    whead_phase(p, sm, p.sW+8, p.dotW, p.pZw, p.wunW, p.pSW, 2, p.wunW+NN, p.pSW+GRIDB);
    g.sync();
    // C1: M0 chain, r(0) partials, write1 -> M1, dots kR1 + kW2
    sweep_phase<1,true,true,true,true,false>(p, sm, 0, p.kR+512, p.sR+8, 3, p.kW+1024, p.sW+16, 4);
    g.sync();
    // D1: w_r(1), w_w(2), rsum r(0)->p2a
    whead_phase(p, sm, p.sR+8, p.dotR, p.pZr, p.wunR, p.pSR, 3, p.wunR+NN, p.pSR+GRIDB);
    whead_phase(p, sm, p.sW+16, p.dotW, p.pZw, p.wunW+NN, p.pSW+GRIDB, 4,
                p.wunW+2*(size_t)NN, p.pSW+2*GRIDB);
    if(bid < 64) rsum1_phase(p, p.p2);
    g.sync();
    // C2: M1 chain, r(1) partials, write2 -> M2, dots kR2 + kW3
    sweep_phase<2,true,true,true,true,false>(p, sm, 1, p.kR+1024, p.sR+16, 5, p.kW+1536, p.sW+24, 6);
    g.sync();
    // D2: w_r(2), w_w(3), rsum r(1)->p2b, h(0)
    whead_phase(p, sm, p.sR+16, p.dotR, p.pZr, p.wunR+NN, p.pSR+GRIDB, 5,
                p.wunR+2*(size_t)NN, p.pSR+2*GRIDB);
    whead_phase(p, sm, p.sW+24, p.dotW, p.pZw, p.wunW+2*(size_t)NN, p.pSW+2*GRIDB, 6,
                p.wunW+3*(size_t)NN, p.pSW+3*GRIDB);
    if(bid < 64) rsum1_phase(p, p.p2 + 64*512);
    if(bid >= 64 && bid < 72) h_phase(p, sm, bid-64, 0, p.p2);
    g.sync();
    // C3: M2 chain, r(2) partials, write3 -> M3, dots kR3
    sweep_phase<3,true,true,true,false,false>(p, sm, 2, p.kR+1536, p.sR+24, 7, nullptr,nullptr,0);
    g.sync();
    // D3: w_r(3), rsum r(2)->p2a, h(1), out(0)
    whead_phase(p, sm, p.sR+24, p.dotR, p.pZr, p.wunR+2*(size_t)NN, p.pSR+2*GRIDB, 7,
                p.wunR+3*(size_t)NN, p.pSR+3*GRIDB);
    if(bid < 64) rsum1_phase(p, p.p2);
    if(bid >= 64 && bid < 72) h_phase(p, sm, bid-64, 1, p.p2 + 64*512);
    if(bid == 72) out_phase(p, 0);
    g.sync();
    // C4: M3 chain, r(3) partials
    sweep_phase<4,true,false,false,false,false>(p, sm, 3, nullptr,nullptr,0, nullptr,nullptr,0);
    g.sync();
    // D4: rsum r(3)->p2b, h(2), out(1)
    if(bid < 64) rsum1_phase(p, p.p2 + 64*512);
    if(bid >= 64 && bid < 72) h_phase(p, sm, bid-64, 2, p.p2);
    if(bid == 72) out_phase(p, 1);
    g.sync();
    // E5: h(3)+out(3) single block; out(2)
    if(bid == 0) hfull_phase(p, sm, 3, p.p2 + 64*512);
    if(bid == 1) out_phase(p, 2);
}

// ================= fallback wrappers (same math, separate launches) ========
__global__ void __launch_bounds__(256) g_owor(KP p){
    __shared__ Smem sm;
    owor_phase(p, sm, blockIdx.x);
}
__global__ void __launch_bounds__(256) g_sweepA(KP p){
    __shared__ Smem sm;
    sweep_phase<0,false,false,false,true,true>(p, sm, 0, nullptr,nullptr,0, p.kW, p.sW, 0);
}
__global__ void __launch_bounds__(256) g_sweepC0(KP p){
    __shared__ Smem sm;
    sweep_phase<0,false,true,true,true,false>(p, sm, 0, p.kR, p.sR, 1, p.kW+512, p.sW+8, 2);
}
__global__ void __launch_bounds__(256) g_sweepC1(KP p){
    __shared__ Smem sm;
    sweep_phase<1,true,true,true,true,false>(p, sm, 0, p.kR+512, p.sR+8, 3, p.kW+1024, p.sW+16, 4);
}
__global__ void __launch_bounds__(256) g_sweepC2(KP p){
    __shared__ Smem sm;
    sweep_phase<2,true,true,true,true,false>(p, sm, 1, p.kR+1024, p.sR+16, 5, p.kW+1536, p.sW+24, 6);
}
__global__ void __launch_bounds__(256) g_sweepC3(KP p){
    __shared__ Smem sm;
    sweep_phase<3,true,true,true,false,false>(p, sm, 2, p.kR+1536, p.sR+24, 7, nullptr,nullptr,0);
}
__global__ void __launch_bounds__(256) g_sweepC4(KP p){
    __shared__ Smem sm;
    sweep_phase<4,true,false,false,false,false>(p, sm, 3, nullptr,nullptr,0, nullptr,nullptr,0);
}
__global__ void __launch_bounds__(256) g_whead(KP p, const float* sV, const float* dotv,
    const float* pZ, const float* wprev, const float* pSprev, int knidx,
    float* wun, float* pSout){
    __shared__ Smem sm;
    whead_phase(p, sm, sV, dotv, pZ, wprev, pSprev, knidx, wun, pSout);
}
__global__ void __launch_bounds__(256) g_rsum1(KP p, float* dst){
    rsum1_phase(p, dst);
}
__global__ void __launch_bounds__(256) g_h(KP p, int step, const float* p2src){
    __shared__ Smem sm;
    h_phase(p, sm, blockIdx.x, step, p2src);
}
__global__ void __launch_bounds__(256) g_out(KP p, int step){
    out_phase(p, step);
}

extern "C" void kernel_launch(void* const* d_in, const int* in_sizes, int n_in,
                              void* d_out, int out_size, void* d_ws, size_t ws_size,
                              hipStream_t stream) {
    const float* x    = (const float*)d_in[0];
    const float* mem0 = (const float*)d_in[1];
    const float* Wc   = (const float*)d_in[2];
    const float* bc   = (const float*)d_in[3];
    const float* Wr   = (const float*)d_in[4];
    const float* br   = (const float*)d_in[5];
    const float* Ww   = (const float*)d_in[6];
    const float* bw   = (const float*)d_in[7];
    const float* W1   = (const float*)d_in[8];
    const float* b1   = (const float*)d_in[9];
    const float* W2   = (const float*)d_in[10];
    const float* b2   = (const float*)d_in[11];

    float* ws = (float*)d_ws;
    size_t off = 0;
    float* mem16 = ws + off; off += (size_t)NN*256;  // 64 MiB fp16 shadow
    float* wunW = ws + off; off += 4*(size_t)NN;
    float* pSW  = ws + off; off += 4*GRIDB;
    float* wunR = ws + off; off += 4*(size_t)NN;
    float* pSR  = ws + off; off += 4*GRIDB;
    float* dotR = ws + off; off += NN;
    float* dotW = ws + off; off += NN;
    float* n2v  = ws + off; off += NN;
    float* pZr  = ws + off; off += GRIDB;
    float* pZw  = ws + off; off += GRIDB;
    float* cont = ws + off; off += 512;
    float* kW   = ws + off; off += 4*512;
    float* sW   = ws + off; off += 4*8;
    float* eW   = ws + off; off += 4*512;
    float* aW   = ws + off; off += 4*512;
    float* kR   = ws + off; off += 4*512;
    float* sR   = ws + off; off += 4*8;
    float* kn   = ws + off; off += 16;
    float* rp   = ws + off; off += (size_t)GRIDB*512;
    float* p2   = ws + off; off += 2*64*512;
    float* hbuf = ws + off; off += 1024;

    KP P;
    P.mem0 = mem0; P.cont = cont; P.mem16 = mem16;
    P.kW = kW; P.sW = sW; P.eW = eW; P.aW = aW; P.kR = kR; P.sR = sR; P.kn = kn;
    P.dotR = dotR; P.dotW = dotW; P.n2v = n2v;
    P.wunW = wunW; P.pSW = pSW; P.wunR = wunR; P.pSR = pSR;
    P.pZr = pZr; P.pZw = pZw;
    P.rp = rp; P.p2 = p2; P.hbuf = hbuf;
    P.W1 = W1; P.b1 = b1; P.W2 = W2; P.b2 = b2;
    P.out = (float*)d_out;
    P.x = x; P.Wc = Wc; P.bc = bc; P.Ww = Ww; P.bw = bw; P.Wr = Wr; P.br = br;
    P.contw = cont; P.kWw = kW; P.sWw = sW; P.eWw = eW; P.aWw = aW;
    P.kRw = kR; P.sRw = sR;

    // ---- cooperative path with safe fallback ----
    bool useCoop = false;
    int coopAttr = 0;
    if(hipDeviceGetAttribute(&coopAttr, hipDeviceAttributeCooperativeLaunch, 0) == hipSuccess
       && coopAttr){
        int nCU = 0, maxb = 0;
        if(hipDeviceGetAttribute(&nCU, hipDeviceAttributeMultiprocessorCount, 0) == hipSuccess
           && hipOccupancyMaxActiveBlocksPerMultiprocessor(&maxb, k_coop, 256, 0) == hipSuccess
           && (long)maxb*(long)nCU >= GRIDB){
            useCoop = true;
        }
    }
    if(useCoop){
        void* args[] = { (void*)&P };
        hipError_t e = hipLaunchCooperativeKernel((const void*)k_coop,
                           dim3(GRIDB), dim3(256), args, 0, stream);
        if(e != hipSuccess){ (void)hipGetLastError(); useCoop = false; }
    }
    if(!useCoop){
        g_owor  <<<33, 256, 0, stream>>>(P);
        g_sweepA<<<GRIDB, 256, 0, stream>>>(P);
        g_whead <<<GRIDB, 256, 0, stream>>>(P, sW, dotW, pZw, nullptr, nullptr, 0, wunW, pSW);
        g_sweepC0<<<GRIDB, 256, 0, stream>>>(P);
        g_whead <<<GRIDB, 256, 0, stream>>>(P, sR, dotR, pZr, nullptr, nullptr, 1, wunR, pSR);
        g_whead <<<GRIDB, 256, 0, stream>>>(P, sW+8, dotW, pZw, wunW, pSW, 2, wunW+NN, pSW+GRIDB);
        g_sweepC1<<<GRIDB, 256, 0, stream>>>(P);
        g_whead <<<GRIDB, 256, 0, stream>>>(P, sR+8, dotR, pZr, wunR, pSR, 3, wunR+NN, pSR+GRIDB);
        g_whead <<<GRIDB, 256, 0, stream>>>(P, sW+16, dotW, pZw, wunW+NN, pSW+GRIDB, 4,
                                            wunW+2*(size_t)NN, pSW+2*GRIDB);
        g_rsum1 <<<64, 256, 0, stream>>>(P, p2);
        g_sweepC2<<<GRIDB, 256, 0, stream>>>(P);
        g_whead <<<GRIDB, 256, 0, stream>>>(P, sR+16, dotR, pZr, wunR+NN, pSR+GRIDB, 5,
                                            wunR+2*(size_t)NN, pSR+2*GRIDB);
        g_whead <<<GRIDB, 256, 0, stream>>>(P, sW+24, dotW, pZw, wunW+2*(size_t)NN, pSW+2*GRIDB, 6,
                                            wunW+3*(size_t)NN, pSW+3*GRIDB);
        g_rsum1 <<<64, 256, 0, stream>>>(P, p2 + 64*512);
        g_h     <<<8, 256, 0, stream>>>(P, 0, p2);
        g_sweepC3<<<GRIDB, 256, 0, stream>>>(P);
        g_whead <<<GRIDB, 256, 0, stream>>>(P, sR+24, dotR, pZr, wunR+2*(size_t)NN, pSR+2*GRIDB, 7,
                                            wunR+3*(size_t)NN, pSR+3*GRIDB);
        g_rsum1 <<<64, 256, 0, stream>>>(P, p2);
        g_h     <<<8, 256, 0, stream>>>(P, 1, p2 + 64*512);
        g_out   <<<1, 256, 0, stream>>>(P, 0);
        g_sweepC4<<<GRIDB, 256, 0, stream>>>(P);
        g_rsum1 <<<64, 256, 0, stream>>>(P, p2 + 64*512);
        g_h     <<<8, 256, 0, stream>>>(P, 2, p2);
        g_out   <<<1, 256, 0, stream>>>(P, 1);
        g_h     <<<8, 256, 0, stream>>>(P, 3, p2 + 64*512);
        g_out   <<<1, 256, 0, stream>>>(P, 2);
        g_out   <<<1, 256, 0, stream>>>(P, 3);
    }
    (void)in_sizes; (void)n_in; (void)out_size; (void)ws_size;
}